// Round 12
// baseline (344.594 us; speedup 1.0000x reference)
//
#include <hip/hip_runtime.h>
#include <hip/hip_bf16.h>

// SDPA causal, B=2 H=16 S=2048 D=64, scale=8. Outputs: attn(f32) ++ out(f32).
// R12: fully barrier-free main kernel. Both phases read K/V fragments direct
// from L2 (pre-swizzled addresses). P buffered 4-deep in LDS per wave; attn
// stores flushed every 4 iters as FULL 1KB-contiguous rows (fill-kernel shape).
#define S_LEN 2048
#define D_HEAD 64
#define SD (S_LEN * D_HEAD)      // 131072 elems per bh
#define TILE_B 8192              // 64x64 bf16 tile bytes
#define NTILES 32                // 64-row tiles per bh

typedef __attribute__((ext_vector_type(8))) short short8;   // 8 bf16 MFMA A/B frag
typedef __attribute__((ext_vector_type(4))) float f32x4;    // MFMA C/D frag

__device__ __forceinline__ unsigned short f2b(float f) {    // fp32 -> bf16 (RNE)
  unsigned int u = __float_as_uint(f);
  u += 0x7fffu + ((u >> 16) & 1u);
  return (unsigned short)(u >> 16);
}

__device__ __forceinline__ float b2f(unsigned short s) {
  return __uint_as_float(((unsigned int)s) << 16);
}

// ---- pre-convert: K tiles swizzled ((s*64+d)*2)^((s&7)<<4);
//      V^T tiles swizzled ((d*64+s)*2)^(((d>>2)&7)<<4) ----
__global__ __launch_bounds__(256) void convert_kv_kernel(
    const float* __restrict__ K, const float* __restrict__ V,
    char* __restrict__ Kpre, char* __restrict__ Vpre) {
  const int bid = blockIdx.x;
  const int tid = threadIdx.x;
  if (bid < 1024) {               // K: (bh,tile), direct chunk permute
    const int bh = bid >> 5, tile = bid & 31;
    const float* Kb = K + (size_t)bh * SD + tile * 64 * 64;
    char* out = Kpre + (size_t)bid * TILE_B;
    #pragma unroll
    for (int j = 0; j < 2; ++j) {
      int c = tid + j * 256;                 // dest 16B-chunk index 0..511
      int sl = c >> 3;                       // row
      int d0 = ((c & 7) ^ (sl & 7)) << 3;    // source d-chunk (inverse swizzle)
      const float* src = Kb + sl * 64 + d0;
      float4 a = *(const float4*)src;
      float4 b = *(const float4*)(src + 4);
      short8 o;
      o[0]=(short)f2b(a.x); o[1]=(short)f2b(a.y); o[2]=(short)f2b(a.z); o[3]=(short)f2b(a.w);
      o[4]=(short)f2b(b.x); o[5]=(short)f2b(b.y); o[6]=(short)f2b(b.z); o[7]=(short)f2b(b.w);
      *(short8*)(out + c * 16) = o;
    }
  } else {                        // V: transpose via padded LDS
    __shared__ float Vl[64][65];
    const int vb = bid - 1024;
    const int bh = vb >> 5, tile = vb & 31;
    const float* Vb = V + (size_t)bh * SD + tile * 64 * 64;
    #pragma unroll
    for (int j = 0; j < 4; ++j) {
      int row = (tid >> 4) + j * 16;
      int c4 = (tid & 15) << 2;
      float4 v = *(const float4*)(Vb + row * 64 + c4);
      Vl[row][c4+0] = v.x; Vl[row][c4+1] = v.y; Vl[row][c4+2] = v.z; Vl[row][c4+3] = v.w;
    }
    __syncthreads();
    char* out = Vpre + (size_t)vb * TILE_B;
    #pragma unroll
    for (int j = 0; j < 2; ++j) {
      int c = tid + j * 256;
      int d = c >> 3;
      int s0 = ((c & 7) ^ ((d >> 2) & 7)) << 3;   // inverse swizzle
      short8 o;
      #pragma unroll
      for (int i = 0; i < 8; ++i) o[i] = (short)f2b(Vl[s0 + i][d]);
      *(short8*)(out + c * 16) = o;
    }
  }
}

__global__ __launch_bounds__(256, 4) void sdpa_pre_kernel(
    const float* __restrict__ Qg, const char* __restrict__ Kpre,
    const char* __restrict__ Vpre, float* __restrict__ attn,
    float* __restrict__ outp) {
  // CU-quad-balanced mapping (round-robin dispatch, XCD = b%8):
  // quad {b, b+256, b+512, b+768} -> same CU, same bh, qt set {u,15-u,16+u,31-u}
  const int j  = blockIdx.x >> 8;          // 0..3
  const int rr = blockIdx.x & 255;
  const int xcd = rr & 7;
  const int cu  = rr >> 3;                 // 0..31
  const int bh  = xcd + ((cu & 3) << 3);   // 0..31, pinned to XCD
  const int u   = cu >> 2;                 // 0..7
  const int qt  = (j == 0) ? u : (j == 1) ? (15 - u) : (j == 2) ? (16 + u) : (31 - u);

  const int tid = threadIdx.x, wave = tid >> 6, lane = tid & 63;
  const int g = lane >> 4, m = lane & 15;
  const int swzK = (m & 7) << 4;

  __shared__ __align__(16) unsigned short Pl[4][4][1024];  // [wave][slot][16x64] = 32KB
  char* const PB = (char*)(&Pl[wave][0][0]);

  const size_t bhSD = (size_t)bh * SD;
  const size_t bhSS = (size_t)bh << 22;
  const char* KpreBH = Kpre + (size_t)bh * NTILES * TILE_B;
  const char* VpreBH = Vpre + (size_t)bh * NTILES * TILE_B;

  int vro[4], vsz[4];
  #pragma unroll
  for (int dc = 0; dc < 4; ++dc) {
    int d = dc * 16 + m;
    vro[dc] = d << 7;
    vsz[dc] = ((d >> 2) & 7) << 4;
  }
  const float SCL = 0.18033688011112042f;   // log2(e)/8

  const int q0 = qt << 6;
  const int nIt = qt + 1;
  const int qwrow = q0 + wave * 16;
  const int qbase = qwrow + g * 4;

  // ---- Q A-fragments (pre-scaled; exp -> exp2) ----
  short8 aq0, aq1;
  {
    const float* qp = Qg + bhSD + (size_t)(qwrow + m) * D_HEAD + g * 8;
    float4 x0 = *(const float4*)(qp);
    float4 x1 = *(const float4*)(qp + 4);
    float4 y0 = *(const float4*)(qp + 32);
    float4 y1 = *(const float4*)(qp + 36);
    aq0[0]=(short)f2b(x0.x*SCL); aq0[1]=(short)f2b(x0.y*SCL);
    aq0[2]=(short)f2b(x0.z*SCL); aq0[3]=(short)f2b(x0.w*SCL);
    aq0[4]=(short)f2b(x1.x*SCL); aq0[5]=(short)f2b(x1.y*SCL);
    aq0[6]=(short)f2b(x1.z*SCL); aq0[7]=(short)f2b(x1.w*SCL);
    aq1[0]=(short)f2b(y0.x*SCL); aq1[1]=(short)f2b(y0.y*SCL);
    aq1[2]=(short)f2b(y0.z*SCL); aq1[3]=(short)f2b(y0.w*SCL);
    aq1[4]=(short)f2b(y1.x*SCL); aq1[5]=(short)f2b(y1.y*SCL);
    aq1[6]=(short)f2b(y1.z*SCL); aq1[7]=(short)f2b(y1.w*SCL);
  }

  // In-tile byte offsets of this thread's 8 K B-frag chunks (swizzle folded in)
  int koffs[8];
  #pragma unroll
  for (int tt = 0; tt < 4; ++tt) {
    const int s = tt * 16 + m;
    const int sw = (s & 7) << 4;
    koffs[2 * tt]     = (s << 7) + ((g * 16) ^ sw);
    koffs[2 * tt + 1] = (s << 7) + ((64 + g * 16) ^ sw);
  }
  // V B-frag offsets (same formula as the old LDS reads; Vpre layout = Vt layout)
  int voffs[8];
  #pragma unroll
  for (int dc = 0; dc < 4; ++dc) {
    voffs[2 * dc]     = vro[dc] + ((g * 16) ^ vsz[dc]);
    voffs[2 * dc + 1] = vro[dc] + ((64 + g * 16) ^ vsz[dc]);
  }

  // ====== Phase 1: row sums of exp — barrier-free, direct-from-L2 ======
  float rs0 = 0.f, rs1 = 0.f, rs2 = 0.f, rs3 = 0.f;
  #pragma unroll 2
  for (int it = 0; it < nIt; ++it) {
    const char* TB = KpreBH + (size_t)it * TILE_B;
    short8 cb[8];
    #pragma unroll
    for (int j2 = 0; j2 < 8; ++j2) cb[j2] = *(const short8*)(TB + koffs[j2]);
    const int kc = it << 6;
    if (kc + 64 <= qwrow) {        // fully unmasked tile (wave-uniform)
      #pragma unroll
      for (int t = 0; t < 4; ++t) {
        f32x4 acc = {0.f, 0.f, 0.f, 0.f};
        acc = __builtin_amdgcn_mfma_f32_16x16x32_bf16(aq0, cb[2 * t], acc, 0, 0, 0);
        acc = __builtin_amdgcn_mfma_f32_16x16x32_bf16(aq1, cb[2 * t + 1], acc, 0, 0, 0);
        rs0 += exp2f(acc[0]);
        rs1 += exp2f(acc[1]);
        rs2 += exp2f(acc[2]);
        rs3 += exp2f(acc[3]);
      }
    } else {
      #pragma unroll
      for (int t = 0; t < 4; ++t) {
        f32x4 acc = {0.f, 0.f, 0.f, 0.f};
        acc = __builtin_amdgcn_mfma_f32_16x16x32_bf16(aq0, cb[2 * t], acc, 0, 0, 0);
        acc = __builtin_amdgcn_mfma_f32_16x16x32_bf16(aq1, cb[2 * t + 1], acc, 0, 0, 0);
        const int kcol = kc + t * 16 + m;
        rs0 += (kcol <= qbase + 0) ? exp2f(acc[0]) : 0.f;
        rs1 += (kcol <= qbase + 1) ? exp2f(acc[1]) : 0.f;
        rs2 += (kcol <= qbase + 2) ? exp2f(acc[2]) : 0.f;
        rs3 += (kcol <= qbase + 3) ? exp2f(acc[3]) : 0.f;
      }
    }
  }
  #pragma unroll
  for (int sft = 1; sft < 16; sft <<= 1) {
    rs0 += __shfl_xor(rs0, sft, 64);
    rs1 += __shfl_xor(rs1, sft, 64);
    rs2 += __shfl_xor(rs2, sft, 64);
    rs3 += __shfl_xor(rs3, sft, 64);
  }
  const float ri0 = 1.f / rs0, ri1 = 1.f / rs1, ri2 = 1.f / rs2, ri3 = 1.f / rs3;

  // ====== Phase 2: recompute, P 4-deep in LDS, flush 1KB-linear rows ======
  f32x4 o0 = {0.f,0.f,0.f,0.f}, o1 = {0.f,0.f,0.f,0.f};
  f32x4 o2 = {0.f,0.f,0.f,0.f}, o3 = {0.f,0.f,0.f,0.f};
  const int fslot = lane >> 4;            // flush: slot index 0..3
  const int fcolb = (lane & 15) << 3;     // flush: byte offset of ushort4 in row
  for (int it = 0; it < nIt; ++it) {
    const char* TB = KpreBH + (size_t)it * TILE_B;
    const char* VG = VpreBH + (size_t)it * TILE_B;
    short8 kb[8], vb8[8];
    #pragma unroll
    for (int j2 = 0; j2 < 8; ++j2) kb[j2] = *(const short8*)(TB + koffs[j2]);
    #pragma unroll
    for (int j2 = 0; j2 < 8; ++j2) vb8[j2] = *(const short8*)(VG + voffs[j2]);
    char* const PS = PB + ((it & 3) << 11);   // this iteration's P slot (2KB)
    const int kc = it << 6;
    if (kc + 64 <= qwrow) {        // fully unmasked tile (wave-uniform)
      #pragma unroll
      for (int t = 0; t < 4; ++t) {
        f32x4 acc = {0.f, 0.f, 0.f, 0.f};
        acc = __builtin_amdgcn_mfma_f32_16x16x32_bf16(aq0, kb[2 * t], acc, 0, 0, 0);
        acc = __builtin_amdgcn_mfma_f32_16x16x32_bf16(aq1, kb[2 * t + 1], acc, 0, 0, 0);
        float p0 = exp2f(acc[0]) * ri0;
        float p1 = exp2f(acc[1]) * ri1;
        float p2 = exp2f(acc[2]) * ri2;
        float p3 = exp2f(acc[3]) * ri3;
        const int r0 = g * 4, c2 = (t * 16 + m) << 1;
        *(unsigned short*)(PS + ((((r0+0)<<7) + c2) ^ (((r0+0)&7)<<4))) = f2b(p0);
        *(unsigned short*)(PS + ((((r0+1)<<7) + c2) ^ (((r0+1)&7)<<4))) = f2b(p1);
        *(unsigned short*)(PS + ((((r0+2)<<7) + c2) ^ (((r0+2)&7)<<4))) = f2b(p2);
        *(unsigned short*)(PS + ((((r0+3)<<7) + c2) ^ (((r0+3)&7)<<4))) = f2b(p3);
      }
    } else {
      #pragma unroll
      for (int t = 0; t < 4; ++t) {
        f32x4 acc = {0.f, 0.f, 0.f, 0.f};
        acc = __builtin_amdgcn_mfma_f32_16x16x32_bf16(aq0, kb[2 * t], acc, 0, 0, 0);
        acc = __builtin_amdgcn_mfma_f32_16x16x32_bf16(aq1, kb[2 * t + 1], acc, 0, 0, 0);
        const int kcol = kc + t * 16 + m;
        float p0 = (kcol <= qbase + 0) ? exp2f(acc[0]) * ri0 : 0.f;
        float p1 = (kcol <= qbase + 1) ? exp2f(acc[1]) * ri1 : 0.f;
        float p2 = (kcol <= qbase + 2) ? exp2f(acc[2]) * ri2 : 0.f;
        float p3 = (kcol <= qbase + 3) ? exp2f(acc[3]) * ri3 : 0.f;
        const int r0 = g * 4, c2 = (t * 16 + m) << 1;
        *(unsigned short*)(PS + ((((r0+0)<<7) + c2) ^ (((r0+0)&7)<<4))) = f2b(p0);
        *(unsigned short*)(PS + ((((r0+1)<<7) + c2) ^ (((r0+1)&7)<<4))) = f2b(p1);
        *(unsigned short*)(PS + ((((r0+2)<<7) + c2) ^ (((r0+2)&7)<<4))) = f2b(p2);
        *(unsigned short*)(PS + ((((r0+3)<<7) + c2) ^ (((r0+3)&7)<<4))) = f2b(p3);
      }
    }
    // PV: A = P rows (row=m) from this slot, B = V^T direct-from-L2 frags
    short8 pa0 = *(const short8*)(PS + (((m << 7) + g * 16) ^ swzK));
    short8 pa1 = *(const short8*)(PS + (((m << 7) + 64 + g * 16) ^ swzK));
    o0 = __builtin_amdgcn_mfma_f32_16x16x32_bf16(pa0, vb8[0], o0, 0, 0, 0);
    o0 = __builtin_amdgcn_mfma_f32_16x16x32_bf16(pa1, vb8[1], o0, 0, 0, 0);
    o1 = __builtin_amdgcn_mfma_f32_16x16x32_bf16(pa0, vb8[2], o1, 0, 0, 0);
    o1 = __builtin_amdgcn_mfma_f32_16x16x32_bf16(pa1, vb8[3], o1, 0, 0, 0);
    o2 = __builtin_amdgcn_mfma_f32_16x16x32_bf16(pa0, vb8[4], o2, 0, 0, 0);
    o2 = __builtin_amdgcn_mfma_f32_16x16x32_bf16(pa1, vb8[5], o2, 0, 0, 0);
    o3 = __builtin_amdgcn_mfma_f32_16x16x32_bf16(pa0, vb8[6], o3, 0, 0, 0);
    o3 = __builtin_amdgcn_mfma_f32_16x16x32_bf16(pa1, vb8[7], o3, 0, 0, 0);
    // Flush every 4 iterations (or at the end): per inst = one row x 1KB linear
    if ((it & 3) == 3 || it == nIt - 1) {
      const int ns = (it & 3) + 1;              // slots to flush
      const int kc0 = (it & ~3) << 6;           // base column of this flush span
      if (fslot < ns) {
        float* fb = attn + bhSS + (size_t)qwrow * S_LEN + kc0 + (fslot << 6);
        const char* PF = PB + (fslot << 11);
        #pragma unroll
        for (int r = 0; r < 16; ++r) {
          ushort4 pr = *(const ushort4*)(PF + (((r << 7) + fcolb) ^ ((r & 7) << 4)));
          float4 fa;
          fa.x = b2f(pr.x); fa.y = b2f(pr.y); fa.z = b2f(pr.z); fa.w = b2f(pr.w);
          *(float4*)(fb + (size_t)r * S_LEN + (fcolb >> 1)) = fa;
        }
      }
    }
  }

  // ---- store O ----
  #pragma unroll
  for (int reg = 0; reg < 4; ++reg) {
    const float rv = (reg == 0) ? 1.f : 1.f;  // (scale already applied)
    (void)rv;
    float* op = outp + bhSD + (size_t)(qbase + reg) * D_HEAD + m;
    op[ 0] = o0[reg];
    op[16] = o1[reg];
    op[32] = o2[reg];
    op[48] = o3[reg];
  }

  // ---- zero-fill cols [kmax, S) for this strip's 64 rows ----
  const int col0 = nIt << 6;
  const int nvec = (S_LEN - col0) >> 2;
  if (nvec > 0) {
    const float4 z = {0.f, 0.f, 0.f, 0.f};
    for (int r = 0; r < 64; ++r) {
      float4* rp = (float4*)(attn + bhSS + (size_t)(q0 + r) * S_LEN + col0);
      for (int i = tid; i < nvec; i += 256) rp[i] = z;
    }
  }
}

// ================== fallback (ws too small): R2 kernel verbatim ==================
__global__ __launch_bounds__(256) void sdpa_fb_kernel(
    const float* __restrict__ Qg, const float* __restrict__ Kg,
    const float* __restrict__ Vg, float* __restrict__ attn,
    float* __restrict__ outp) {
  const int bh = blockIdx.x >> 4;
  const int pi = blockIdx.x & 15;
  const int tid  = threadIdx.x;
  const int wave = tid >> 6;
  const int lane = tid & 63;
  const int g = lane >> 4;
  const int m = lane & 15;
  const int swzK = (m & 7) << 4;
  __shared__ __align__(16) unsigned short Kl[2][64 * 64];
  __shared__ __align__(16) unsigned short Vt[2][64 * 64];
  __shared__ __align__(16) unsigned short Pl[4][16 * 64];
  char* const PB = (char*)(&Pl[wave][0]);
  const size_t bhSD = (size_t)bh * (S_LEN * D_HEAD);
  const size_t bhSS = (size_t)bh * ((size_t)S_LEN * S_LEN);
  int ss[4], dd[4], koff[4];
  #pragma unroll
  for (int j = 0; j < 4; ++j) {
    int f = tid + j * 256;
    ss[j] = f >> 4;
    dd[j] = (f & 15) << 2;
    koff[j] = (((ss[j] << 6) + dd[j]) << 1) ^ ((ss[j] & 7) << 4);
  }
  int vro[4], vsz[4];
  #pragma unroll
  for (int dc = 0; dc < 4; ++dc) {
    int d = dc * 16 + m;
    vro[dc] = d << 7;
    vsz[dc] = ((d >> 2) & 7) << 4;
  }
  const float SCL = 0.18033688011112042f;
  for (int sidx = 0; sidx < 2; ++sidx) {
    const int qt = sidx ? (31 - pi) : pi;
    const int q0 = qt << 6;
    const int kmax = q0 + 64;
    const int nIter = kmax >> 6;
    const int qwrow = q0 + wave * 16;
    const int qbase = qwrow + g * 4;
    short8 aq0, aq1;
    {
      const float* qp = Qg + bhSD + (size_t)(qwrow + m) * D_HEAD + g * 8;
      float4 x0 = *(const float4*)(qp);
      float4 x1 = *(const float4*)(qp + 4);
      float4 y0 = *(const float4*)(qp + 32);
      float4 y1 = *(const float4*)(qp + 36);
      aq0[0]=(short)f2b(x0.x*SCL); aq0[1]=(short)f2b(x0.y*SCL);
      aq0[2]=(short)f2b(x0.z*SCL); aq0[3]=(short)f2b(x0.w*SCL);
      aq0[4]=(short)f2b(x1.x*SCL); aq0[5]=(short)f2b(x1.y*SCL);
      aq0[6]=(short)f2b(x1.z*SCL); aq0[7]=(short)f2b(x1.w*SCL);
      aq1[0]=(short)f2b(y0.x*SCL); aq1[1]=(short)f2b(y0.y*SCL);
      aq1[2]=(short)f2b(y0.z*SCL); aq1[3]=(short)f2b(y0.w*SCL);
      aq1[4]=(short)f2b(y1.x*SCL); aq1[5]=(short)f2b(y1.y*SCL);
      aq1[6]=(short)f2b(y1.z*SCL); aq1[7]=(short)f2b(y1.w*SCL);
    }
    float rs0 = 0.f, rs1 = 0.f, rs2 = 0.f, rs3 = 0.f;
    {
      float4 kr[4];
      #pragma unroll
      for (int j = 0; j < 4; ++j)
        kr[j] = *(const float4*)(Kg + bhSD + (size_t)ss[j] * D_HEAD + dd[j]);
      #pragma unroll
      for (int j = 0; j < 4; ++j) {
        ushort4 kb;
        kb.x = f2b(kr[j].x); kb.y = f2b(kr[j].y);
        kb.z = f2b(kr[j].z); kb.w = f2b(kr[j].w);
        *(ushort4*)((char*)Kl[0] + koff[j]) = kb;
      }
    }
    __syncthreads();
    int cur = 0;
    for (int it = 0; it < nIter; ++it) {
      const int kc = it << 6;
      const bool pf = (it + 1 < nIter);
      float4 kr[4];
      if (pf) {
        #pragma unroll
        for (int j = 0; j < 4; ++j)
          kr[j] = *(const float4*)(Kg + bhSD + (size_t)(kc + 64 + ss[j]) * D_HEAD + dd[j]);
      }
      const char* KB = (const char*)Kl[cur];
      #pragma unroll
      for (int t = 0; t < 4; ++t) {
        f32x4 acc = {0.f, 0.f, 0.f, 0.f};
        const int rb = (t * 16 + m) << 7;
        short8 b0 = *(const short8*)(KB + ((rb + g * 16) ^ swzK));
        short8 b1 = *(const short8*)(KB + ((rb + 64 + g * 16) ^ swzK));
        acc = __builtin_amdgcn_mfma_f32_16x16x32_bf16(aq0, b0, acc, 0, 0, 0);
        acc = __builtin_amdgcn_mfma_f32_16x16x32_bf16(aq1, b1, acc, 0, 0, 0);
        const int kcol = kc + t * 16 + m;
        rs0 += (kcol <= qbase + 0) ? exp2f(acc[0]) : 0.f;
        rs1 += (kcol <= qbase + 1) ? exp2f(acc[1]) : 0.f;
        rs2 += (kcol <= qbase + 2) ? exp2f(acc[2]) : 0.f;
        rs3 += (kcol <= qbase + 3) ? exp2f(acc[3]) : 0.f;
      }
      if (pf) {
        #pragma unroll
        for (int j = 0; j < 4; ++j) {
          ushort4 kb;
          kb.x = f2b(kr[j].x); kb.y = f2b(kr[j].y);
          kb.z = f2b(kr[j].z); kb.w = f2b(kr[j].w);
          *(ushort4*)((char*)Kl[cur ^ 1] + koff[j]) = kb;
        }
      }
      __syncthreads();
      cur ^= 1;
    }
    #pragma unroll
    for (int sft = 1; sft < 16; sft <<= 1) {
      rs0 += __shfl_xor(rs0, sft, 64);
      rs1 += __shfl_xor(rs1, sft, 64);
      rs2 += __shfl_xor(rs2, sft, 64);
      rs3 += __shfl_xor(rs3, sft, 64);
    }
    const float ri0 = 1.f / rs0, ri1 = 1.f / rs1, ri2 = 1.f / rs2, ri3 = 1.f / rs3;
    f32x4 o0 = {0.f,0.f,0.f,0.f}, o1 = {0.f,0.f,0.f,0.f};
    f32x4 o2 = {0.f,0.f,0.f,0.f}, o3 = {0.f,0.f,0.f,0.f};
    {
      float4 kr[4], vr[4];
      #pragma unroll
      for (int j = 0; j < 4; ++j) {
        kr[j] = *(const float4*)(Kg + bhSD + (size_t)ss[j] * D_HEAD + dd[j]);
        vr[j] = *(const float4*)(Vg + bhSD + (size_t)ss[j] * D_HEAD + dd[j]);
      }
      #pragma unroll
      for (int j = 0; j < 4; ++j) {
        ushort4 kb;
        kb.x = f2b(kr[j].x); kb.y = f2b(kr[j].y);
        kb.z = f2b(kr[j].z); kb.w = f2b(kr[j].w);
        *(ushort4*)((char*)Kl[0] + koff[j]) = kb;
        const int d0 = dd[j], s2 = ss[j] << 1;
        char* VB1 = (char*)Vt[0];
        *(unsigned short*)(VB1 + ((((d0+0)<<7) + s2) ^ ((((d0+0)>>2)&7)<<4))) = f2b(vr[j].x);
        *(unsigned short*)(VB1 + ((((d0+1)<<7) + s2) ^ ((((d0+1)>>2)&7)<<4))) = f2b(vr[j].y);
        *(unsigned short*)(VB1 + ((((d0+2)<<7) + s2) ^ ((((d0+2)>>2)&7)<<4))) = f2b(vr[j].z);
        *(unsigned short*)(VB1 + ((((d0+3)<<7) + s2) ^ ((((d0+3)>>2)&7)<<4))) = f2b(vr[j].w);
      }
    }
    __syncthreads();
    cur = 0;
    for (int it = 0; it < nIter; ++it) {
      const int kc = it << 6;
      const bool pf = (it + 1 < nIter);
      float4 kr[4], vr[4];
      if (pf) {
        #pragma unroll
        for (int j = 0; j < 4; ++j) {
          kr[j] = *(const float4*)(Kg + bhSD + (size_t)(kc + 64 + ss[j]) * D_HEAD + dd[j]);
          vr[j] = *(const float4*)(Vg + bhSD + (size_t)(kc + 64 + ss[j]) * D_HEAD + dd[j]);
        }
      }
      const char* KB = (const char*)Kl[cur];
      const char* VB = (const char*)Vt[cur];
      float* arow = attn + bhSS + (size_t)qbase * S_LEN + kc;
      #pragma unroll
      for (int t = 0; t < 4; ++t) {
        f32x4 acc = {0.f, 0.f, 0.f, 0.f};
        const int rb = (t * 16 + m) << 7;
        short8 b0 = *(const short8*)(KB + ((rb + g * 16) ^ swzK));
        short8 b1 = *(const short8*)(KB + ((rb + 64 + g * 16) ^ swzK));
        acc = __builtin_amdgcn_mfma_f32_16x16x32_bf16(aq0, b0, acc, 0, 0, 0);
        acc = __builtin_amdgcn_mfma_f32_16x16x32_bf16(aq1, b1, acc, 0, 0, 0);
        const int kcol = kc + t * 16 + m;
        const int tc = t * 16 + m;
        float p0 = (kcol <= qbase + 0) ? exp2f(acc[0]) * ri0 : 0.f;
        float p1 = (kcol <= qbase + 1) ? exp2f(acc[1]) * ri1 : 0.f;
        float p2 = (kcol <= qbase + 2) ? exp2f(acc[2]) * ri2 : 0.f;
        float p3 = (kcol <= qbase + 3) ? exp2f(acc[3]) * ri3 : 0.f;
        arow[0 * S_LEN + tc] = p0;
        arow[1 * S_LEN + tc] = p1;
        arow[2 * S_LEN + tc] = p2;
        arow[3 * S_LEN + tc] = p3;
        const int r0 = g * 4, c2 = tc << 1;
        *(unsigned short*)(PB + ((((r0+0)<<7) + c2) ^ (((r0+0)&7)<<4))) = f2b(p0);
        *(unsigned short*)(PB + ((((r0+1)<<7) + c2) ^ (((r0+1)&7)<<4))) = f2b(p1);
        *(unsigned short*)(PB + ((((r0+2)<<7) + c2) ^ (((r0+2)&7)<<4))) = f2b(p2);
        *(unsigned short*)(PB + ((((r0+3)<<7) + c2) ^ (((r0+3)&7)<<4))) = f2b(p3);
      }
      short8 pa0 = *(const short8*)(PB + (((m << 7) + g * 16) ^ swzK));
      short8 pa1 = *(const short8*)(PB + (((m << 7) + 64 + g * 16) ^ swzK));
      #pragma unroll
      for (int dc = 0; dc < 4; ++dc) {
        short8 bv0 = *(const short8*)(VB + ((vro[dc] + g * 16) ^ vsz[dc]));
        short8 bv1 = *(const short8*)(VB + ((vro[dc] + 64 + g * 16) ^ vsz[dc]));
        f32x4& od = (dc == 0) ? o0 : (dc == 1) ? o1 : (dc == 2) ? o2 : o3;
        od = __builtin_amdgcn_mfma_f32_16x16x32_bf16(pa0, bv0, od, 0, 0, 0);
        od = __builtin_amdgcn_mfma_f32_16x16x32_bf16(pa1, bv1, od, 0, 0, 0);
      }
      if (pf) {
        #pragma unroll
        for (int j = 0; j < 4; ++j) {
          ushort4 kb;
          kb.x = f2b(kr[j].x); kb.y = f2b(kr[j].y);
          kb.z = f2b(kr[j].z); kb.w = f2b(kr[j].w);
          *(ushort4*)((char*)Kl[cur ^ 1] + koff[j]) = kb;
          const int d0 = dd[j], s2 = ss[j] << 1;
          char* VB1 = (char*)Vt[cur ^ 1];
          *(unsigned short*)(VB1 + ((((d0+0)<<7) + s2) ^ ((((d0+0)>>2)&7)<<4))) = f2b(vr[j].x);
          *(unsigned short*)(VB1 + ((((d0+1)<<7) + s2) ^ ((((d0+1)>>2)&7)<<4))) = f2b(vr[j].y);
          *(unsigned short*)(VB1 + ((((d0+2)<<7) + s2) ^ ((((d0+2)>>2)&7)<<4))) = f2b(vr[j].z);
          *(unsigned short*)(VB1 + ((((d0+3)<<7) + s2) ^ ((((d0+3)>>2)&7)<<4))) = f2b(vr[j].w);
        }
      }
      __syncthreads();
      cur ^= 1;
    }
    #pragma unroll
    for (int reg = 0; reg < 4; ++reg) {
      float* op = outp + bhSD + (size_t)(qbase + reg) * D_HEAD + m;
      op[ 0] = o0[reg];
      op[16] = o1[reg];
      op[32] = o2[reg];
      op[48] = o3[reg];
    }
    const int ncols = S_LEN - kmax;
    if (ncols > 0) {
      const float4 z = {0.f, 0.f, 0.f, 0.f};
      const int nvec = ncols >> 2;
      for (int r = 0; r < 64; ++r) {
        float4* rp = (float4*)(attn + bhSS + (size_t)(q0 + r) * S_LEN + kmax);
        for (int i = tid; i < nvec; i += 256) rp[i] = z;
      }
    }
  }
}

extern "C" void kernel_launch(void* const* d_in, const int* in_sizes, int n_in,
                              void* d_out, int out_size, void* d_ws, size_t ws_size,
                              hipStream_t stream) {
  (void)in_sizes; (void)n_in; (void)out_size;
  const float* q = (const float*)d_in[0];
  const float* k = (const float*)d_in[1];
  const float* v = (const float*)d_in[2];
  float* attn = (float*)d_out;
  float* outp = attn + (size_t)2 * 16 * 2048 * 2048;
  const size_t pre_bytes = (size_t)32 * NTILES * TILE_B;   // 8.39 MB per tensor
  if (ws_size >= 2 * pre_bytes) {
    char* Kpre = (char*)d_ws;
    char* Vpre = Kpre + pre_bytes;
    convert_kv_kernel<<<2048, 256, 0, stream>>>(k, v, Kpre, Vpre);
    sdpa_pre_kernel<<<1024, 256, 0, stream>>>(q, Kpre, Vpre, attn, outp);
  } else {
    sdpa_fb_kernel<<<512, 256, 0, stream>>>(q, k, v, attn, outp);
  }
}

// Round 14
// 152.633 us; speedup vs baseline: 2.2577x; 2.2577x over previous
//
#include <hip/hip_runtime.h>
#include <hip/hip_bf16.h>

// SDPA causal, B=2 H=16 S=2048 D=64, scale=8. Outputs: attn(f32) ++ out(f32).
// R14 = R13 with the NT-store type fixed (clang ext_vector f32x4, not HIP float4).
// R9 structure (ring-4 phase 1, staged dbuf phase 2, full-line stores, tail
// fill) + NON-TEMPORAL stores for all outputs: the 554MB write stream was
// thrashing L2 / evicting Kpre/Vpre (R12 counters: FETCH_SIZE 240-594MB).
#define S_LEN 2048
#define D_HEAD 64
#define SD (S_LEN * D_HEAD)      // 131072 elems per bh
#define TILE_B 8192              // 64x64 bf16 tile bytes
#define NTILES 32                // 64-row tiles per bh

typedef __attribute__((ext_vector_type(8))) short short8;   // 8 bf16 MFMA A/B frag
typedef __attribute__((ext_vector_type(4))) float f32x4;    // MFMA C/D frag

__device__ __forceinline__ unsigned short f2b(float f) {    // fp32 -> bf16 (RNE)
  unsigned int u = __float_as_uint(f);
  u += 0x7fffu + ((u >> 16) & 1u);
  return (unsigned short)(u >> 16);
}

__device__ __forceinline__ float b2f(unsigned short s) {
  return __uint_as_float(((unsigned int)s) << 16);
}

__device__ __forceinline__ void nt_store4(float* p, f32x4 v) {
  __builtin_nontemporal_store(v, (f32x4*)p);
}

__device__ __forceinline__ void gl_lds16(const void* g, void* l) {
  __builtin_amdgcn_global_load_lds(
      (const __attribute__((address_space(1))) unsigned int*)g,
      (__attribute__((address_space(3))) unsigned int*)l, 16, 0, 0);
}

// stage one 8KB tile: 256 thr x 2 insts; LDS linear, source pre-swizzled
__device__ __forceinline__ void stage8k(const char* gsrc, char* ldst, int w, int lane) {
  gl_lds16(gsrc + ((w * 64 + lane) << 4),        ldst + ((w * 64) << 4));
  gl_lds16(gsrc + ((256 + w * 64 + lane) << 4),  ldst + ((256 + w * 64) << 4));
}

// ---- pre-convert: K tiles swizzled ((s*64+d)*2)^((s&7)<<4);
//      V^T tiles swizzled ((d*64+s)*2)^(((d>>2)&7)<<4) ----
__global__ __launch_bounds__(256) void convert_kv_kernel(
    const float* __restrict__ K, const float* __restrict__ V,
    char* __restrict__ Kpre, char* __restrict__ Vpre) {
  const int bid = blockIdx.x;
  const int tid = threadIdx.x;
  if (bid < 1024) {               // K: (bh,tile), direct chunk permute
    const int bh = bid >> 5, tile = bid & 31;
    const float* Kb = K + (size_t)bh * SD + tile * 64 * 64;
    char* out = Kpre + (size_t)bid * TILE_B;
    #pragma unroll
    for (int j = 0; j < 2; ++j) {
      int c = tid + j * 256;                 // dest 16B-chunk index 0..511
      int sl = c >> 3;                       // row
      int d0 = ((c & 7) ^ (sl & 7)) << 3;    // source d-chunk (inverse swizzle)
      const float* src = Kb + sl * 64 + d0;
      float4 a = *(const float4*)src;
      float4 b = *(const float4*)(src + 4);
      short8 o;
      o[0]=(short)f2b(a.x); o[1]=(short)f2b(a.y); o[2]=(short)f2b(a.z); o[3]=(short)f2b(a.w);
      o[4]=(short)f2b(b.x); o[5]=(short)f2b(b.y); o[6]=(short)f2b(b.z); o[7]=(short)f2b(b.w);
      *(short8*)(out + c * 16) = o;
    }
  } else {                        // V: transpose via padded LDS
    __shared__ float Vl[64][65];
    const int vb = bid - 1024;
    const int bh = vb >> 5, tile = vb & 31;
    const float* Vb = V + (size_t)bh * SD + tile * 64 * 64;
    #pragma unroll
    for (int j = 0; j < 4; ++j) {
      int row = (tid >> 4) + j * 16;
      int c4 = (tid & 15) << 2;
      float4 v = *(const float4*)(Vb + row * 64 + c4);
      Vl[row][c4+0] = v.x; Vl[row][c4+1] = v.y; Vl[row][c4+2] = v.z; Vl[row][c4+3] = v.w;
    }
    __syncthreads();
    char* out = Vpre + (size_t)vb * TILE_B;
    #pragma unroll
    for (int j = 0; j < 2; ++j) {
      int c = tid + j * 256;
      int d = c >> 3;
      int s0 = ((c & 7) ^ ((d >> 2) & 7)) << 3;   // inverse swizzle
      short8 o;
      #pragma unroll
      for (int i = 0; i < 8; ++i) o[i] = (short)f2b(Vl[s0 + i][d]);
      *(short8*)(out + c * 16) = o;
    }
  }
}

__global__ __launch_bounds__(256, 4) void sdpa_pre_kernel(
    const float* __restrict__ Qg, const char* __restrict__ Kpre,
    const char* __restrict__ Vpre, float* __restrict__ attn,
    float* __restrict__ outp) {
  // CU-quad-balanced mapping (round-robin dispatch, XCD = b%8):
  // quad {b, b+256, b+512, b+768} -> same CU, same bh, qt set {u,15-u,16+u,31-u}
  const int j  = blockIdx.x >> 8;          // 0..3
  const int rr = blockIdx.x & 255;
  const int xcd = rr & 7;
  const int cu  = rr >> 3;                 // 0..31
  const int bh  = xcd + ((cu & 3) << 3);   // 0..31, pinned to XCD
  const int u   = cu >> 2;                 // 0..7
  const int qt  = (j == 0) ? u : (j == 1) ? (15 - u) : (j == 2) ? (16 + u) : (31 - u);

  const int tid = threadIdx.x, wave = tid >> 6, lane = tid & 63;
  const int g = lane >> 4, m = lane & 15;
  const int swzK = (m & 7) << 4;

  __shared__ __align__(16) unsigned short Ring[4][4096];  // 32KB: ph1 ring / ph2 K0,K1,V0,V1
  __shared__ __align__(16) unsigned short Pl[4][1024];    // 4 x 2KB per-wave P
  char* const RB = (char*)Ring;
  char* const PB = (char*)(&Pl[wave][0]);

  const size_t bhSD = (size_t)bh * SD;
  const size_t bhSS = (size_t)bh << 22;
  const char* KpreBH = Kpre + (size_t)bh * NTILES * TILE_B;
  const char* VpreBH = Vpre + (size_t)bh * NTILES * TILE_B;

  int vro[4], vsz[4];
  #pragma unroll
  for (int dc = 0; dc < 4; ++dc) {
    int d = dc * 16 + m;
    vro[dc] = d << 7;
    vsz[dc] = ((d >> 2) & 7) << 4;
  }
  const float SCL = 0.18033688011112042f;   // log2(e)/8

  const int q0 = qt << 6;
  const int nIt = qt + 1;
  const int qwrow = q0 + wave * 16;
  const int qbase = qwrow + g * 4;

  // ---- Q A-fragments (pre-scaled; exp -> exp2) ----
  short8 aq0, aq1;
  {
    const float* qp = Qg + bhSD + (size_t)(qwrow + m) * D_HEAD + g * 8;
    float4 x0 = *(const float4*)(qp);
    float4 x1 = *(const float4*)(qp + 4);
    float4 y0 = *(const float4*)(qp + 32);
    float4 y1 = *(const float4*)(qp + 36);
    aq0[0]=(short)f2b(x0.x*SCL); aq0[1]=(short)f2b(x0.y*SCL);
    aq0[2]=(short)f2b(x0.z*SCL); aq0[3]=(short)f2b(x0.w*SCL);
    aq0[4]=(short)f2b(x1.x*SCL); aq0[5]=(short)f2b(x1.y*SCL);
    aq0[6]=(short)f2b(x1.z*SCL); aq0[7]=(short)f2b(x1.w*SCL);
    aq1[0]=(short)f2b(y0.x*SCL); aq1[1]=(short)f2b(y0.y*SCL);
    aq1[2]=(short)f2b(y0.z*SCL); aq1[3]=(short)f2b(y0.w*SCL);
    aq1[4]=(short)f2b(y1.x*SCL); aq1[5]=(short)f2b(y1.y*SCL);
    aq1[6]=(short)f2b(y1.z*SCL); aq1[7]=(short)f2b(y1.w*SCL);
  }

  // ====== Phase 1: row sums of exp (ring-4 K prefetch, no stores) ======
  float rs0 = 0.f, rs1 = 0.f, rs2 = 0.f, rs3 = 0.f;
  {
    const int npre = nIt < 3 ? nIt : 3;
    for (int t0 = 0; t0 < npre; ++t0)
      stage8k(KpreBH + (size_t)t0 * TILE_B, RB + t0 * TILE_B, wave, lane);
  }
  for (int it = 0; it < nIt; ++it) {
    if (it + 2 < nIt)      { asm volatile("s_waitcnt vmcnt(4)" ::: "memory"); }
    else if (it + 1 < nIt) { asm volatile("s_waitcnt vmcnt(2)" ::: "memory"); }
    else                   { asm volatile("s_waitcnt vmcnt(0)" ::: "memory"); }
    __builtin_amdgcn_s_barrier();
    __builtin_amdgcn_sched_barrier(0);
    if (it + 3 < nIt)
      stage8k(KpreBH + (size_t)(it + 3) * TILE_B, RB + ((it + 3) & 3) * TILE_B, wave, lane);
    asm volatile("" ::: "memory");
    const char* KB = RB + (it & 3) * TILE_B;
    const int kc = it << 6;
    if (kc + 64 <= qwrow) {        // fully unmasked tile (wave-uniform)
      #pragma unroll
      for (int t = 0; t < 4; ++t) {
        f32x4 acc = {0.f, 0.f, 0.f, 0.f};
        const int rb = (t * 16 + m) << 7;
        short8 b0 = *(const short8*)(KB + ((rb + g * 16) ^ swzK));
        short8 b1 = *(const short8*)(KB + ((rb + 64 + g * 16) ^ swzK));
        acc = __builtin_amdgcn_mfma_f32_16x16x32_bf16(aq0, b0, acc, 0, 0, 0);
        acc = __builtin_amdgcn_mfma_f32_16x16x32_bf16(aq1, b1, acc, 0, 0, 0);
        rs0 += exp2f(acc[0]);
        rs1 += exp2f(acc[1]);
        rs2 += exp2f(acc[2]);
        rs3 += exp2f(acc[3]);
      }
    } else {
      #pragma unroll
      for (int t = 0; t < 4; ++t) {
        f32x4 acc = {0.f, 0.f, 0.f, 0.f};
        const int rb = (t * 16 + m) << 7;
        short8 b0 = *(const short8*)(KB + ((rb + g * 16) ^ swzK));
        short8 b1 = *(const short8*)(KB + ((rb + 64 + g * 16) ^ swzK));
        acc = __builtin_amdgcn_mfma_f32_16x16x32_bf16(aq0, b0, acc, 0, 0, 0);
        acc = __builtin_amdgcn_mfma_f32_16x16x32_bf16(aq1, b1, acc, 0, 0, 0);
        const int kcol = kc + t * 16 + m;
        rs0 += (kcol <= qbase + 0) ? exp2f(acc[0]) : 0.f;
        rs1 += (kcol <= qbase + 1) ? exp2f(acc[1]) : 0.f;
        rs2 += (kcol <= qbase + 2) ? exp2f(acc[2]) : 0.f;
        rs3 += (kcol <= qbase + 3) ? exp2f(acc[3]) : 0.f;
      }
    }
  }
  #pragma unroll
  for (int sft = 1; sft < 16; sft <<= 1) {
    rs0 += __shfl_xor(rs0, sft, 64);
    rs1 += __shfl_xor(rs1, sft, 64);
    rs2 += __shfl_xor(rs2, sft, 64);
    rs3 += __shfl_xor(rs3, sft, 64);
  }
  const float ri0 = 1.f / rs0, ri1 = 1.f / rs1, ri2 = 1.f / rs2, ri3 = 1.f / rs3;

  // ====== Phase 2: recompute, write attn (full-line NT stores), accumulate O ======
  f32x4 o0 = {0.f,0.f,0.f,0.f}, o1 = {0.f,0.f,0.f,0.f};
  f32x4 o2 = {0.f,0.f,0.f,0.f}, o3 = {0.f,0.f,0.f,0.f};
  __builtin_amdgcn_s_barrier();   // all waves done reading phase-1 ring
  stage8k(KpreBH, RB + 0 * TILE_B, wave, lane);            // K -> Ring[cur]
  stage8k(VpreBH, RB + 2 * TILE_B, wave, lane);            // V -> Ring[2+cur]
  int cur = 0;
  const int r4 = lane >> 4;        // store row-subgroup (0..3)
  const int cf = (lane & 15) << 2; // store col (float) 0..60
  for (int it = 0; it < nIt; ++it) {
    if (it == 0) { asm volatile("s_waitcnt vmcnt(0)" ::: "memory"); }
    else         { asm volatile("s_waitcnt vmcnt(4)" ::: "memory"); }
    __builtin_amdgcn_s_barrier();
    __builtin_amdgcn_sched_barrier(0);
    if (it + 1 < nIt) {                       // 4 vm loads, FIRST vm ops of iter
      stage8k(KpreBH + (size_t)(it + 1) * TILE_B, RB + (cur ^ 1) * TILE_B, wave, lane);
      stage8k(VpreBH + (size_t)(it + 1) * TILE_B, RB + (2 + (cur ^ 1)) * TILE_B, wave, lane);
    }
    asm volatile("" ::: "memory");
    const char* KB = RB + cur * TILE_B;
    const char* VB = RB + (2 + cur) * TILE_B;
    const int kc = it << 6;
    if (kc + 64 <= qwrow) {        // fully unmasked tile (wave-uniform)
      #pragma unroll
      for (int t = 0; t < 4; ++t) {
        f32x4 acc = {0.f, 0.f, 0.f, 0.f};
        const int rb = (t * 16 + m) << 7;
        short8 b0 = *(const short8*)(KB + ((rb + g * 16) ^ swzK));
        short8 b1 = *(const short8*)(KB + ((rb + 64 + g * 16) ^ swzK));
        acc = __builtin_amdgcn_mfma_f32_16x16x32_bf16(aq0, b0, acc, 0, 0, 0);
        acc = __builtin_amdgcn_mfma_f32_16x16x32_bf16(aq1, b1, acc, 0, 0, 0);
        float p0 = exp2f(acc[0]) * ri0;
        float p1 = exp2f(acc[1]) * ri1;
        float p2 = exp2f(acc[2]) * ri2;
        float p3 = exp2f(acc[3]) * ri3;
        const int r0 = g * 4, c2 = (t * 16 + m) << 1;
        *(unsigned short*)(PB + ((((r0+0)<<7) + c2) ^ (((r0+0)&7)<<4))) = f2b(p0);
        *(unsigned short*)(PB + ((((r0+1)<<7) + c2) ^ (((r0+1)&7)<<4))) = f2b(p1);
        *(unsigned short*)(PB + ((((r0+2)<<7) + c2) ^ (((r0+2)&7)<<4))) = f2b(p2);
        *(unsigned short*)(PB + ((((r0+3)<<7) + c2) ^ (((r0+3)&7)<<4))) = f2b(p3);
      }
    } else {
      #pragma unroll
      for (int t = 0; t < 4; ++t) {
        f32x4 acc = {0.f, 0.f, 0.f, 0.f};
        const int rb = (t * 16 + m) << 7;
        short8 b0 = *(const short8*)(KB + ((rb + g * 16) ^ swzK));
        short8 b1 = *(const short8*)(KB + ((rb + 64 + g * 16) ^ swzK));
        acc = __builtin_amdgcn_mfma_f32_16x16x32_bf16(aq0, b0, acc, 0, 0, 0);
        acc = __builtin_amdgcn_mfma_f32_16x16x32_bf16(aq1, b1, acc, 0, 0, 0);
        const int kcol = kc + t * 16 + m;
        float p0 = (kcol <= qbase + 0) ? exp2f(acc[0]) * ri0 : 0.f;
        float p1 = (kcol <= qbase + 1) ? exp2f(acc[1]) * ri1 : 0.f;
        float p2 = (kcol <= qbase + 2) ? exp2f(acc[2]) * ri2 : 0.f;
        float p3 = (kcol <= qbase + 3) ? exp2f(acc[3]) * ri3 : 0.f;
        const int r0 = g * 4, c2 = (t * 16 + m) << 1;
        *(unsigned short*)(PB + ((((r0+0)<<7) + c2) ^ (((r0+0)&7)<<4))) = f2b(p0);
        *(unsigned short*)(PB + ((((r0+1)<<7) + c2) ^ (((r0+1)&7)<<4))) = f2b(p1);
        *(unsigned short*)(PB + ((((r0+2)<<7) + c2) ^ (((r0+2)&7)<<4))) = f2b(p2);
        *(unsigned short*)(PB + ((((r0+3)<<7) + c2) ^ (((r0+3)&7)<<4))) = f2b(p3);
      }
    }
    // attn NT stores from P-LDS: each inst = 4 rows x 256B contiguous (full lines)
    {
      float* abase2 = attn + bhSS + (size_t)qwrow * S_LEN + kc;
      #pragma unroll
      for (int jj = 0; jj < 4; ++jj) {
        const int row = 4 * jj + r4;
        const int off = (((row << 7) + (cf << 1))) ^ ((row & 7) << 4);
        ushort4 pr = *(const ushort4*)(PB + off);
        f32x4 fa;
        fa[0] = b2f(pr.x); fa[1] = b2f(pr.y); fa[2] = b2f(pr.z); fa[3] = b2f(pr.w);
        nt_store4(abase2 + (size_t)row * S_LEN + cf, fa);
      }
    }
    // PV: A = P rows (row=m), B = V^T (row=d)
    short8 pa0 = *(const short8*)(PB + (((m << 7) + g * 16) ^ swzK));
    short8 pa1 = *(const short8*)(PB + (((m << 7) + 64 + g * 16) ^ swzK));
    #pragma unroll
    for (int dc = 0; dc < 4; ++dc) {
      short8 bv0 = *(const short8*)(VB + ((vro[dc] + g * 16) ^ vsz[dc]));
      short8 bv1 = *(const short8*)(VB + ((vro[dc] + 64 + g * 16) ^ vsz[dc]));
      f32x4& od = (dc == 0) ? o0 : (dc == 1) ? o1 : (dc == 2) ? o2 : o3;
      od = __builtin_amdgcn_mfma_f32_16x16x32_bf16(pa0, bv0, od, 0, 0, 0);
      od = __builtin_amdgcn_mfma_f32_16x16x32_bf16(pa1, bv1, od, 0, 0, 0);
    }
    cur ^= 1;
  }

  // ---- store O (non-temporal scalar stores) ----
  #pragma unroll
  for (int reg = 0; reg < 4; ++reg) {
    float* op = outp + bhSD + (size_t)(qbase + reg) * D_HEAD + m;
    __builtin_nontemporal_store(o0[reg], op +  0);
    __builtin_nontemporal_store(o1[reg], op + 16);
    __builtin_nontemporal_store(o2[reg], op + 32);
    __builtin_nontemporal_store(o3[reg], op + 48);
  }

  // ---- zero-fill cols [kmax, S) for this strip's 64 rows (NT stores) ----
  const int col0 = nIt << 6;
  const int nvec = (S_LEN - col0) >> 2;
  if (nvec > 0) {
    const f32x4 z = {0.f, 0.f, 0.f, 0.f};
    for (int r = 0; r < 64; ++r) {
      float* rp = attn + bhSS + (size_t)(q0 + r) * S_LEN + col0;
      for (int i = tid; i < nvec; i += 256) nt_store4(rp + i * 4, z);
    }
  }
}

// ================== fallback (ws too small): R2 kernel verbatim ==================
__global__ __launch_bounds__(256) void sdpa_fb_kernel(
    const float* __restrict__ Qg, const float* __restrict__ Kg,
    const float* __restrict__ Vg, float* __restrict__ attn,
    float* __restrict__ outp) {
  const int bh = blockIdx.x >> 4;
  const int pi = blockIdx.x & 15;
  const int tid  = threadIdx.x;
  const int wave = tid >> 6;
  const int lane = tid & 63;
  const int g = lane >> 4;
  const int m = lane & 15;
  const int swzK = (m & 7) << 4;
  __shared__ __align__(16) unsigned short Kl[2][64 * 64];
  __shared__ __align__(16) unsigned short Vt[2][64 * 64];
  __shared__ __align__(16) unsigned short Pl[4][16 * 64];
  char* const PB = (char*)(&Pl[wave][0]);
  const size_t bhSD = (size_t)bh * (S_LEN * D_HEAD);
  const size_t bhSS = (size_t)bh * ((size_t)S_LEN * S_LEN);
  int ss[4], dd[4], koff[4];
  #pragma unroll
  for (int j = 0; j < 4; ++j) {
    int f = tid + j * 256;
    ss[j] = f >> 4;
    dd[j] = (f & 15) << 2;
    koff[j] = (((ss[j] << 6) + dd[j]) << 1) ^ ((ss[j] & 7) << 4);
  }
  int vro[4], vsz[4];
  #pragma unroll
  for (int dc = 0; dc < 4; ++dc) {
    int d = dc * 16 + m;
    vro[dc] = d << 7;
    vsz[dc] = ((d >> 2) & 7) << 4;
  }
  const float SCL = 0.18033688011112042f;
  for (int sidx = 0; sidx < 2; ++sidx) {
    const int qt = sidx ? (31 - pi) : pi;
    const int q0 = qt << 6;
    const int kmax = q0 + 64;
    const int nIter = kmax >> 6;
    const int qwrow = q0 + wave * 16;
    const int qbase = qwrow + g * 4;
    short8 aq0, aq1;
    {
      const float* qp = Qg + bhSD + (size_t)(qwrow + m) * D_HEAD + g * 8;
      float4 x0 = *(const float4*)(qp);
      float4 x1 = *(const float4*)(qp + 4);
      float4 y0 = *(const float4*)(qp + 32);
      float4 y1 = *(const float4*)(qp + 36);
      aq0[0]=(short)f2b(x0.x*SCL); aq0[1]=(short)f2b(x0.y*SCL);
      aq0[2]=(short)f2b(x0.z*SCL); aq0[3]=(short)f2b(x0.w*SCL);
      aq0[4]=(short)f2b(x1.x*SCL); aq0[5]=(short)f2b(x1.y*SCL);
      aq0[6]=(short)f2b(x1.z*SCL); aq0[7]=(short)f2b(x1.w*SCL);
      aq1[0]=(short)f2b(y0.x*SCL); aq1[1]=(short)f2b(y0.y*SCL);
      aq1[2]=(short)f2b(y0.z*SCL); aq1[3]=(short)f2b(y0.w*SCL);
      aq1[4]=(short)f2b(y1.x*SCL); aq1[5]=(short)f2b(y1.y*SCL);
      aq1[6]=(short)f2b(y1.z*SCL); aq1[7]=(short)f2b(y1.w*SCL);
    }
    float rs0 = 0.f, rs1 = 0.f, rs2 = 0.f, rs3 = 0.f;
    {
      float4 kr[4];
      #pragma unroll
      for (int j = 0; j < 4; ++j)
        kr[j] = *(const float4*)(Kg + bhSD + (size_t)ss[j] * D_HEAD + dd[j]);
      #pragma unroll
      for (int j = 0; j < 4; ++j) {
        ushort4 kb;
        kb.x = f2b(kr[j].x); kb.y = f2b(kr[j].y);
        kb.z = f2b(kr[j].z); kb.w = f2b(kr[j].w);
        *(ushort4*)((char*)Kl[0] + koff[j]) = kb;
      }
    }
    __syncthreads();
    int cur = 0;
    for (int it = 0; it < nIter; ++it) {
      const int kc = it << 6;
      const bool pf = (it + 1 < nIter);
      float4 kr[4];
      if (pf) {
        #pragma unroll
        for (int j = 0; j < 4; ++j)
          kr[j] = *(const float4*)(Kg + bhSD + (size_t)(kc + 64 + ss[j]) * D_HEAD + dd[j]);
      }
      const char* KB = (const char*)Kl[cur];
      #pragma unroll
      for (int t = 0; t < 4; ++t) {
        f32x4 acc = {0.f, 0.f, 0.f, 0.f};
        const int rb = (t * 16 + m) << 7;
        short8 b0 = *(const short8*)(KB + ((rb + g * 16) ^ swzK));
        short8 b1 = *(const short8*)(KB + ((rb + 64 + g * 16) ^ swzK));
        acc = __builtin_amdgcn_mfma_f32_16x16x32_bf16(aq0, b0, acc, 0, 0, 0);
        acc = __builtin_amdgcn_mfma_f32_16x16x32_bf16(aq1, b1, acc, 0, 0, 0);
        const int kcol = kc + t * 16 + m;
        rs0 += (kcol <= qbase + 0) ? exp2f(acc[0]) : 0.f;
        rs1 += (kcol <= qbase + 1) ? exp2f(acc[1]) : 0.f;
        rs2 += (kcol <= qbase + 2) ? exp2f(acc[2]) : 0.f;
        rs3 += (kcol <= qbase + 3) ? exp2f(acc[3]) : 0.f;
      }
      if (pf) {
        #pragma unroll
        for (int j = 0; j < 4; ++j) {
          ushort4 kb;
          kb.x = f2b(kr[j].x); kb.y = f2b(kr[j].y);
          kb.z = f2b(kr[j].z); kb.w = f2b(kr[j].w);
          *(ushort4*)((char*)Kl[cur ^ 1] + koff[j]) = kb;
        }
      }
      __syncthreads();
      cur ^= 1;
    }
    #pragma unroll
    for (int sft = 1; sft < 16; sft <<= 1) {
      rs0 += __shfl_xor(rs0, sft, 64);
      rs1 += __shfl_xor(rs1, sft, 64);
      rs2 += __shfl_xor(rs2, sft, 64);
      rs3 += __shfl_xor(rs3, sft, 64);
    }
    const float ri0 = 1.f / rs0, ri1 = 1.f / rs1, ri2 = 1.f / rs2, ri3 = 1.f / rs3;
    f32x4 o0 = {0.f,0.f,0.f,0.f}, o1 = {0.f,0.f,0.f,0.f};
    f32x4 o2 = {0.f,0.f,0.f,0.f}, o3 = {0.f,0.f,0.f,0.f};
    {
      float4 kr[4], vr[4];
      #pragma unroll
      for (int j = 0; j < 4; ++j) {
        kr[j] = *(const float4*)(Kg + bhSD + (size_t)ss[j] * D_HEAD + dd[j]);
        vr[j] = *(const float4*)(Vg + bhSD + (size_t)ss[j] * D_HEAD + dd[j]);
      }
      #pragma unroll
      for (int j = 0; j < 4; ++j) {
        ushort4 kb;
        kb.x = f2b(kr[j].x); kb.y = f2b(kr[j].y);
        kb.z = f2b(kr[j].z); kb.w = f2b(kr[j].w);
        *(ushort4*)((char*)Kl[0] + koff[j]) = kb;
        const int d0 = dd[j], s2 = ss[j] << 1;
        char* VB1 = (char*)Vt[0];
        *(unsigned short*)(VB1 + ((((d0+0)<<7) + s2) ^ ((((d0+0)>>2)&7)<<4))) = f2b(vr[j].x);
        *(unsigned short*)(VB1 + ((((d0+1)<<7) + s2) ^ ((((d0+1)>>2)&7)<<4))) = f2b(vr[j].y);
        *(unsigned short*)(VB1 + ((((d0+2)<<7) + s2) ^ ((((d0+2)>>2)&7)<<4))) = f2b(vr[j].z);
        *(unsigned short*)(VB1 + ((((d0+3)<<7) + s2) ^ ((((d0+3)>>2)&7)<<4))) = f2b(vr[j].w);
      }
    }
    __syncthreads();
    cur = 0;
    for (int it = 0; it < nIter; ++it) {
      const int kc = it << 6;
      const bool pf = (it + 1 < nIter);
      float4 kr[4], vr[4];
      if (pf) {
        #pragma unroll
        for (int j = 0; j < 4; ++j) {
          kr[j] = *(const float4*)(Kg + bhSD + (size_t)(kc + 64 + ss[j]) * D_HEAD + dd[j]);
          vr[j] = *(const float4*)(Vg + bhSD + (size_t)(kc + 64 + ss[j]) * D_HEAD + dd[j]);
        }
      }
      const char* KB = (const char*)Kl[cur];
      const char* VB = (const char*)Vt[cur];
      float* arow = attn + bhSS + (size_t)qbase * S_LEN + kc;
      #pragma unroll
      for (int t = 0; t < 4; ++t) {
        f32x4 acc = {0.f, 0.f, 0.f, 0.f};
        const int rb = (t * 16 + m) << 7;
        short8 b0 = *(const short8*)(KB + ((rb + g * 16) ^ swzK));
        short8 b1 = *(const short8*)(KB + ((rb + 64 + g * 16) ^ swzK));
        acc = __builtin_amdgcn_mfma_f32_16x16x32_bf16(aq0, b0, acc, 0, 0, 0);
        acc = __builtin_amdgcn_mfma_f32_16x16x32_bf16(aq1, b1, acc, 0, 0, 0);
        const int kcol = kc + t * 16 + m;
        const int tc = t * 16 + m;
        float p0 = (kcol <= qbase + 0) ? exp2f(acc[0]) * ri0 : 0.f;
        float p1 = (kcol <= qbase + 1) ? exp2f(acc[1]) * ri1 : 0.f;
        float p2 = (kcol <= qbase + 2) ? exp2f(acc[2]) * ri2 : 0.f;
        float p3 = (kcol <= qbase + 3) ? exp2f(acc[3]) * ri3 : 0.f;
        arow[0 * S_LEN + tc] = p0;
        arow[1 * S_LEN + tc] = p1;
        arow[2 * S_LEN + tc] = p2;
        arow[3 * S_LEN + tc] = p3;
        const int r0 = g * 4, c2 = tc << 1;
        *(unsigned short*)(PB + ((((r0+0)<<7) + c2) ^ (((r0+0)&7)<<4))) = f2b(p0);
        *(unsigned short*)(PB + ((((r0+1)<<7) + c2) ^ (((r0+1)&7)<<4))) = f2b(p1);
        *(unsigned short*)(PB + ((((r0+2)<<7) + c2) ^ (((r0+2)&7)<<4))) = f2b(p2);
        *(unsigned short*)(PB + ((((r0+3)<<7) + c2) ^ (((r0+3)&7)<<4))) = f2b(p3);
      }
      short8 pa0 = *(const short8*)(PB + (((m << 7) + g * 16) ^ swzK));
      short8 pa1 = *(const short8*)(PB + (((m << 7) + 64 + g * 16) ^ swzK));
      #pragma unroll
      for (int dc = 0; dc < 4; ++dc) {
        short8 bv0 = *(const short8*)(VB + ((vro[dc] + g * 16) ^ vsz[dc]));
        short8 bv1 = *(const short8*)(VB + ((vro[dc] + 64 + g * 16) ^ vsz[dc]));
        f32x4& od = (dc == 0) ? o0 : (dc == 1) ? o1 : (dc == 2) ? o2 : o3;
        od = __builtin_amdgcn_mfma_f32_16x16x32_bf16(pa0, bv0, od, 0, 0, 0);
        od = __builtin_amdgcn_mfma_f32_16x16x32_bf16(pa1, bv1, od, 0, 0, 0);
      }
      if (pf) {
        #pragma unroll
        for (int j = 0; j < 4; ++j) {
          ushort4 kb;
          kb.x = f2b(kr[j].x); kb.y = f2b(kr[j].y);
          kb.z = f2b(kr[j].z); kb.w = f2b(kr[j].w);
          *(ushort4*)((char*)Kl[cur ^ 1] + koff[j]) = kb;
          const int d0 = dd[j], s2 = ss[j] << 1;
          char* VB1 = (char*)Vt[cur ^ 1];
          *(unsigned short*)(VB1 + ((((d0+0)<<7) + s2) ^ ((((d0+0)>>2)&7)<<4))) = f2b(vr[j].x);
          *(unsigned short*)(VB1 + ((((d0+1)<<7) + s2) ^ ((((d0+1)>>2)&7)<<4))) = f2b(vr[j].y);
          *(unsigned short*)(VB1 + ((((d0+2)<<7) + s2) ^ ((((d0+2)>>2)&7)<<4))) = f2b(vr[j].z);
          *(unsigned short*)(VB1 + ((((d0+3)<<7) + s2) ^ ((((d0+3)>>2)&7)<<4))) = f2b(vr[j].w);
        }
      }
      __syncthreads();
      cur ^= 1;
    }
    #pragma unroll
    for (int reg = 0; reg < 4; ++reg) {
      float* op = outp + bhSD + (size_t)(qbase + reg) * D_HEAD + m;
      op[ 0] = o0[reg];
      op[16] = o1[reg];
      op[32] = o2[reg];
      op[48] = o3[reg];
    }
    const int ncols = S_LEN - kmax;
    if (ncols > 0) {
      const float4 z = {0.f, 0.f, 0.f, 0.f};
      const int nvec = ncols >> 2;
      for (int r = 0; r < 64; ++r) {
        float4* rp = (float4*)(attn + bhSS + (size_t)(q0 + r) * S_LEN + kmax);
        for (int i = tid; i < nvec; i += 256) rp[i] = z;
      }
    }
  }
}

extern "C" void kernel_launch(void* const* d_in, const int* in_sizes, int n_in,
                              void* d_out, int out_size, void* d_ws, size_t ws_size,
                              hipStream_t stream) {
  (void)in_sizes; (void)n_in; (void)out_size;
  const float* q = (const float*)d_in[0];
  const float* k = (const float*)d_in[1];
  const float* v = (const float*)d_in[2];
  float* attn = (float*)d_out;
  float* outp = attn + (size_t)2 * 16 * 2048 * 2048;
  const size_t pre_bytes = (size_t)32 * NTILES * TILE_B;   // 8.39 MB per tensor
  if (ws_size >= 2 * pre_bytes) {
    char* Kpre = (char*)d_ws;
    char* Vpre = Kpre + pre_bytes;
    convert_kv_kernel<<<2048, 256, 0, stream>>>(k, v, Kpre, Vpre);
    sdpa_pre_kernel<<<1024, 256, 0, stream>>>(q, Kpre, Vpre, attn, outp);
  } else {
    sdpa_fb_kernel<<<512, 256, 0, stream>>>(q, k, v, attn, outp);
  }
}

// Round 15
// 152.418 us; speedup vs baseline: 2.2608x; 1.0014x over previous
//
#include <hip/hip_runtime.h>
#include <hip/hip_bf16.h>

// SDPA causal, B=2 H=16 S=2048 D=64, scale=8. Outputs: attn(f32) ++ out(f32).
// R15 = R14 with phase-2 steady-state wait vmcnt(4) -> vmcnt(16): the old count
// force-drained 12 of the 16 NT attn stores every iteration (stores are YOUNGER
// than the staging loads in the vm queue; waiting for the 4 loads only needs
// outstanding <= 16). NT stores retire at HBM latency, so the over-drain stalled
// each iteration.
#define S_LEN 2048
#define D_HEAD 64
#define SD (S_LEN * D_HEAD)      // 131072 elems per bh
#define TILE_B 8192              // 64x64 bf16 tile bytes
#define NTILES 32                // 64-row tiles per bh

typedef __attribute__((ext_vector_type(8))) short short8;   // 8 bf16 MFMA A/B frag
typedef __attribute__((ext_vector_type(4))) float f32x4;    // MFMA C/D frag

__device__ __forceinline__ unsigned short f2b(float f) {    // fp32 -> bf16 (RNE)
  unsigned int u = __float_as_uint(f);
  u += 0x7fffu + ((u >> 16) & 1u);
  return (unsigned short)(u >> 16);
}

__device__ __forceinline__ float b2f(unsigned short s) {
  return __uint_as_float(((unsigned int)s) << 16);
}

__device__ __forceinline__ void nt_store4(float* p, f32x4 v) {
  __builtin_nontemporal_store(v, (f32x4*)p);
}

__device__ __forceinline__ void gl_lds16(const void* g, void* l) {
  __builtin_amdgcn_global_load_lds(
      (const __attribute__((address_space(1))) unsigned int*)g,
      (__attribute__((address_space(3))) unsigned int*)l, 16, 0, 0);
}

// stage one 8KB tile: 256 thr x 2 insts; LDS linear, source pre-swizzled
__device__ __forceinline__ void stage8k(const char* gsrc, char* ldst, int w, int lane) {
  gl_lds16(gsrc + ((w * 64 + lane) << 4),        ldst + ((w * 64) << 4));
  gl_lds16(gsrc + ((256 + w * 64 + lane) << 4),  ldst + ((256 + w * 64) << 4));
}

// ---- pre-convert: K tiles swizzled ((s*64+d)*2)^((s&7)<<4);
//      V^T tiles swizzled ((d*64+s)*2)^(((d>>2)&7)<<4) ----
__global__ __launch_bounds__(256) void convert_kv_kernel(
    const float* __restrict__ K, const float* __restrict__ V,
    char* __restrict__ Kpre, char* __restrict__ Vpre) {
  const int bid = blockIdx.x;
  const int tid = threadIdx.x;
  if (bid < 1024) {               // K: (bh,tile), direct chunk permute
    const int bh = bid >> 5, tile = bid & 31;
    const float* Kb = K + (size_t)bh * SD + tile * 64 * 64;
    char* out = Kpre + (size_t)bid * TILE_B;
    #pragma unroll
    for (int j = 0; j < 2; ++j) {
      int c = tid + j * 256;                 // dest 16B-chunk index 0..511
      int sl = c >> 3;                       // row
      int d0 = ((c & 7) ^ (sl & 7)) << 3;    // source d-chunk (inverse swizzle)
      const float* src = Kb + sl * 64 + d0;
      float4 a = *(const float4*)src;
      float4 b = *(const float4*)(src + 4);
      short8 o;
      o[0]=(short)f2b(a.x); o[1]=(short)f2b(a.y); o[2]=(short)f2b(a.z); o[3]=(short)f2b(a.w);
      o[4]=(short)f2b(b.x); o[5]=(short)f2b(b.y); o[6]=(short)f2b(b.z); o[7]=(short)f2b(b.w);
      *(short8*)(out + c * 16) = o;
    }
  } else {                        // V: transpose via padded LDS
    __shared__ float Vl[64][65];
    const int vb = bid - 1024;
    const int bh = vb >> 5, tile = vb & 31;
    const float* Vb = V + (size_t)bh * SD + tile * 64 * 64;
    #pragma unroll
    for (int j = 0; j < 4; ++j) {
      int row = (tid >> 4) + j * 16;
      int c4 = (tid & 15) << 2;
      float4 v = *(const float4*)(Vb + row * 64 + c4);
      Vl[row][c4+0] = v.x; Vl[row][c4+1] = v.y; Vl[row][c4+2] = v.z; Vl[row][c4+3] = v.w;
    }
    __syncthreads();
    char* out = Vpre + (size_t)vb * TILE_B;
    #pragma unroll
    for (int j = 0; j < 2; ++j) {
      int c = tid + j * 256;
      int d = c >> 3;
      int s0 = ((c & 7) ^ ((d >> 2) & 7)) << 3;   // inverse swizzle
      short8 o;
      #pragma unroll
      for (int i = 0; i < 8; ++i) o[i] = (short)f2b(Vl[s0 + i][d]);
      *(short8*)(out + c * 16) = o;
    }
  }
}

__global__ __launch_bounds__(256, 4) void sdpa_pre_kernel(
    const float* __restrict__ Qg, const char* __restrict__ Kpre,
    const char* __restrict__ Vpre, float* __restrict__ attn,
    float* __restrict__ outp) {
  // CU-quad-balanced mapping (round-robin dispatch, XCD = b%8):
  // quad {b, b+256, b+512, b+768} -> same CU, same bh, qt set {u,15-u,16+u,31-u}
  const int j  = blockIdx.x >> 8;          // 0..3
  const int rr = blockIdx.x & 255;
  const int xcd = rr & 7;
  const int cu  = rr >> 3;                 // 0..31
  const int bh  = xcd + ((cu & 3) << 3);   // 0..31, pinned to XCD
  const int u   = cu >> 2;                 // 0..7
  const int qt  = (j == 0) ? u : (j == 1) ? (15 - u) : (j == 2) ? (16 + u) : (31 - u);

  const int tid = threadIdx.x, wave = tid >> 6, lane = tid & 63;
  const int g = lane >> 4, m = lane & 15;
  const int swzK = (m & 7) << 4;

  __shared__ __align__(16) unsigned short Ring[4][4096];  // 32KB: ph1 ring / ph2 K0,K1,V0,V1
  __shared__ __align__(16) unsigned short Pl[4][1024];    // 4 x 2KB per-wave P
  char* const RB = (char*)Ring;
  char* const PB = (char*)(&Pl[wave][0]);

  const size_t bhSD = (size_t)bh * SD;
  const size_t bhSS = (size_t)bh << 22;
  const char* KpreBH = Kpre + (size_t)bh * NTILES * TILE_B;
  const char* VpreBH = Vpre + (size_t)bh * NTILES * TILE_B;

  int vro[4], vsz[4];
  #pragma unroll
  for (int dc = 0; dc < 4; ++dc) {
    int d = dc * 16 + m;
    vro[dc] = d << 7;
    vsz[dc] = ((d >> 2) & 7) << 4;
  }
  const float SCL = 0.18033688011112042f;   // log2(e)/8

  const int q0 = qt << 6;
  const int nIt = qt + 1;
  const int qwrow = q0 + wave * 16;
  const int qbase = qwrow + g * 4;

  // ---- Q A-fragments (pre-scaled; exp -> exp2) ----
  short8 aq0, aq1;
  {
    const float* qp = Qg + bhSD + (size_t)(qwrow + m) * D_HEAD + g * 8;
    float4 x0 = *(const float4*)(qp);
    float4 x1 = *(const float4*)(qp + 4);
    float4 y0 = *(const float4*)(qp + 32);
    float4 y1 = *(const float4*)(qp + 36);
    aq0[0]=(short)f2b(x0.x*SCL); aq0[1]=(short)f2b(x0.y*SCL);
    aq0[2]=(short)f2b(x0.z*SCL); aq0[3]=(short)f2b(x0.w*SCL);
    aq0[4]=(short)f2b(x1.x*SCL); aq0[5]=(short)f2b(x1.y*SCL);
    aq0[6]=(short)f2b(x1.z*SCL); aq0[7]=(short)f2b(x1.w*SCL);
    aq1[0]=(short)f2b(y0.x*SCL); aq1[1]=(short)f2b(y0.y*SCL);
    aq1[2]=(short)f2b(y0.z*SCL); aq1[3]=(short)f2b(y0.w*SCL);
    aq1[4]=(short)f2b(y1.x*SCL); aq1[5]=(short)f2b(y1.y*SCL);
    aq1[6]=(short)f2b(y1.z*SCL); aq1[7]=(short)f2b(y1.w*SCL);
  }

  // ====== Phase 1: row sums of exp (ring-4 K prefetch, no stores) ======
  float rs0 = 0.f, rs1 = 0.f, rs2 = 0.f, rs3 = 0.f;
  {
    const int npre = nIt < 3 ? nIt : 3;
    for (int t0 = 0; t0 < npre; ++t0)
      stage8k(KpreBH + (size_t)t0 * TILE_B, RB + t0 * TILE_B, wave, lane);
  }
  for (int it = 0; it < nIt; ++it) {
    if (it + 2 < nIt)      { asm volatile("s_waitcnt vmcnt(4)" ::: "memory"); }
    else if (it + 1 < nIt) { asm volatile("s_waitcnt vmcnt(2)" ::: "memory"); }
    else                   { asm volatile("s_waitcnt vmcnt(0)" ::: "memory"); }
    __builtin_amdgcn_s_barrier();
    __builtin_amdgcn_sched_barrier(0);
    if (it + 3 < nIt)
      stage8k(KpreBH + (size_t)(it + 3) * TILE_B, RB + ((it + 3) & 3) * TILE_B, wave, lane);
    asm volatile("" ::: "memory");
    const char* KB = RB + (it & 3) * TILE_B;
    const int kc = it << 6;
    if (kc + 64 <= qwrow) {        // fully unmasked tile (wave-uniform)
      #pragma unroll
      for (int t = 0; t < 4; ++t) {
        f32x4 acc = {0.f, 0.f, 0.f, 0.f};
        const int rb = (t * 16 + m) << 7;
        short8 b0 = *(const short8*)(KB + ((rb + g * 16) ^ swzK));
        short8 b1 = *(const short8*)(KB + ((rb + 64 + g * 16) ^ swzK));
        acc = __builtin_amdgcn_mfma_f32_16x16x32_bf16(aq0, b0, acc, 0, 0, 0);
        acc = __builtin_amdgcn_mfma_f32_16x16x32_bf16(aq1, b1, acc, 0, 0, 0);
        rs0 += exp2f(acc[0]);
        rs1 += exp2f(acc[1]);
        rs2 += exp2f(acc[2]);
        rs3 += exp2f(acc[3]);
      }
    } else {
      #pragma unroll
      for (int t = 0; t < 4; ++t) {
        f32x4 acc = {0.f, 0.f, 0.f, 0.f};
        const int rb = (t * 16 + m) << 7;
        short8 b0 = *(const short8*)(KB + ((rb + g * 16) ^ swzK));
        short8 b1 = *(const short8*)(KB + ((rb + 64 + g * 16) ^ swzK));
        acc = __builtin_amdgcn_mfma_f32_16x16x32_bf16(aq0, b0, acc, 0, 0, 0);
        acc = __builtin_amdgcn_mfma_f32_16x16x32_bf16(aq1, b1, acc, 0, 0, 0);
        const int kcol = kc + t * 16 + m;
        rs0 += (kcol <= qbase + 0) ? exp2f(acc[0]) : 0.f;
        rs1 += (kcol <= qbase + 1) ? exp2f(acc[1]) : 0.f;
        rs2 += (kcol <= qbase + 2) ? exp2f(acc[2]) : 0.f;
        rs3 += (kcol <= qbase + 3) ? exp2f(acc[3]) : 0.f;
      }
    }
  }
  #pragma unroll
  for (int sft = 1; sft < 16; sft <<= 1) {
    rs0 += __shfl_xor(rs0, sft, 64);
    rs1 += __shfl_xor(rs1, sft, 64);
    rs2 += __shfl_xor(rs2, sft, 64);
    rs3 += __shfl_xor(rs3, sft, 64);
  }
  const float ri0 = 1.f / rs0, ri1 = 1.f / rs1, ri2 = 1.f / rs2, ri3 = 1.f / rs3;

  // ====== Phase 2: recompute, write attn (full-line NT stores), accumulate O ======
  f32x4 o0 = {0.f,0.f,0.f,0.f}, o1 = {0.f,0.f,0.f,0.f};
  f32x4 o2 = {0.f,0.f,0.f,0.f}, o3 = {0.f,0.f,0.f,0.f};
  __builtin_amdgcn_s_barrier();   // all waves done reading phase-1 ring
  stage8k(KpreBH, RB + 0 * TILE_B, wave, lane);            // K -> Ring[cur]
  stage8k(VpreBH, RB + 2 * TILE_B, wave, lane);            // V -> Ring[2+cur]
  int cur = 0;
  const int r4 = lane >> 4;        // store row-subgroup (0..3)
  const int cf = (lane & 15) << 2; // store col (float) 0..60
  for (int it = 0; it < nIt; ++it) {
    if (it == 0) { asm volatile("s_waitcnt vmcnt(0)" ::: "memory"); }
    else         { asm volatile("s_waitcnt vmcnt(16)" ::: "memory"); }  // loads are the
    // oldest 4 of [4 loads][16 NT stores]; allow all 16 stores to stay in flight
    __builtin_amdgcn_s_barrier();
    __builtin_amdgcn_sched_barrier(0);
    if (it + 1 < nIt) {                       // 4 vm loads, FIRST vm ops of iter
      stage8k(KpreBH + (size_t)(it + 1) * TILE_B, RB + (cur ^ 1) * TILE_B, wave, lane);
      stage8k(VpreBH + (size_t)(it + 1) * TILE_B, RB + (2 + (cur ^ 1)) * TILE_B, wave, lane);
    }
    asm volatile("" ::: "memory");
    const char* KB = RB + cur * TILE_B;
    const char* VB = RB + (2 + cur) * TILE_B;
    const int kc = it << 6;
    if (kc + 64 <= qwrow) {        // fully unmasked tile (wave-uniform)
      #pragma unroll
      for (int t = 0; t < 4; ++t) {
        f32x4 acc = {0.f, 0.f, 0.f, 0.f};
        const int rb = (t * 16 + m) << 7;
        short8 b0 = *(const short8*)(KB + ((rb + g * 16) ^ swzK));
        short8 b1 = *(const short8*)(KB + ((rb + 64 + g * 16) ^ swzK));
        acc = __builtin_amdgcn_mfma_f32_16x16x32_bf16(aq0, b0, acc, 0, 0, 0);
        acc = __builtin_amdgcn_mfma_f32_16x16x32_bf16(aq1, b1, acc, 0, 0, 0);
        float p0 = exp2f(acc[0]) * ri0;
        float p1 = exp2f(acc[1]) * ri1;
        float p2 = exp2f(acc[2]) * ri2;
        float p3 = exp2f(acc[3]) * ri3;
        const int r0 = g * 4, c2 = (t * 16 + m) << 1;
        *(unsigned short*)(PB + ((((r0+0)<<7) + c2) ^ (((r0+0)&7)<<4))) = f2b(p0);
        *(unsigned short*)(PB + ((((r0+1)<<7) + c2) ^ (((r0+1)&7)<<4))) = f2b(p1);
        *(unsigned short*)(PB + ((((r0+2)<<7) + c2) ^ (((r0+2)&7)<<4))) = f2b(p2);
        *(unsigned short*)(PB + ((((r0+3)<<7) + c2) ^ (((r0+3)&7)<<4))) = f2b(p3);
      }
    } else {
      #pragma unroll
      for (int t = 0; t < 4; ++t) {
        f32x4 acc = {0.f, 0.f, 0.f, 0.f};
        const int rb = (t * 16 + m) << 7;
        short8 b0 = *(const short8*)(KB + ((rb + g * 16) ^ swzK));
        short8 b1 = *(const short8*)(KB + ((rb + 64 + g * 16) ^ swzK));
        acc = __builtin_amdgcn_mfma_f32_16x16x32_bf16(aq0, b0, acc, 0, 0, 0);
        acc = __builtin_amdgcn_mfma_f32_16x16x32_bf16(aq1, b1, acc, 0, 0, 0);
        const int kcol = kc + t * 16 + m;
        float p0 = (kcol <= qbase + 0) ? exp2f(acc[0]) * ri0 : 0.f;
        float p1 = (kcol <= qbase + 1) ? exp2f(acc[1]) * ri1 : 0.f;
        float p2 = (kcol <= qbase + 2) ? exp2f(acc[2]) * ri2 : 0.f;
        float p3 = (kcol <= qbase + 3) ? exp2f(acc[3]) * ri3 : 0.f;
        const int r0 = g * 4, c2 = (t * 16 + m) << 1;
        *(unsigned short*)(PB + ((((r0+0)<<7) + c2) ^ (((r0+0)&7)<<4))) = f2b(p0);
        *(unsigned short*)(PB + ((((r0+1)<<7) + c2) ^ (((r0+1)&7)<<4))) = f2b(p1);
        *(unsigned short*)(PB + ((((r0+2)<<7) + c2) ^ (((r0+2)&7)<<4))) = f2b(p2);
        *(unsigned short*)(PB + ((((r0+3)<<7) + c2) ^ (((r0+3)&7)<<4))) = f2b(p3);
      }
    }
    // attn NT stores from P-LDS: each inst = 4 rows x 256B contiguous (full lines)
    {
      float* abase2 = attn + bhSS + (size_t)qwrow * S_LEN + kc;
      #pragma unroll
      for (int jj = 0; jj < 4; ++jj) {
        const int row = 4 * jj + r4;
        const int off = (((row << 7) + (cf << 1))) ^ ((row & 7) << 4);
        ushort4 pr = *(const ushort4*)(PB + off);
        f32x4 fa;
        fa[0] = b2f(pr.x); fa[1] = b2f(pr.y); fa[2] = b2f(pr.z); fa[3] = b2f(pr.w);
        nt_store4(abase2 + (size_t)row * S_LEN + cf, fa);
      }
    }
    // PV: A = P rows (row=m), B = V^T (row=d)
    short8 pa0 = *(const short8*)(PB + (((m << 7) + g * 16) ^ swzK));
    short8 pa1 = *(const short8*)(PB + (((m << 7) + 64 + g * 16) ^ swzK));
    #pragma unroll
    for (int dc = 0; dc < 4; ++dc) {
      short8 bv0 = *(const short8*)(VB + ((vro[dc] + g * 16) ^ vsz[dc]));
      short8 bv1 = *(const short8*)(VB + ((vro[dc] + 64 + g * 16) ^ vsz[dc]));
      f32x4& od = (dc == 0) ? o0 : (dc == 1) ? o1 : (dc == 2) ? o2 : o3;
      od = __builtin_amdgcn_mfma_f32_16x16x32_bf16(pa0, bv0, od, 0, 0, 0);
      od = __builtin_amdgcn_mfma_f32_16x16x32_bf16(pa1, bv1, od, 0, 0, 0);
    }
    cur ^= 1;
  }

  // ---- store O (non-temporal scalar stores) ----
  #pragma unroll
  for (int reg = 0; reg < 4; ++reg) {
    float* op = outp + bhSD + (size_t)(qbase + reg) * D_HEAD + m;
    __builtin_nontemporal_store(o0[reg], op +  0);
    __builtin_nontemporal_store(o1[reg], op + 16);
    __builtin_nontemporal_store(o2[reg], op + 32);
    __builtin_nontemporal_store(o3[reg], op + 48);
  }

  // ---- zero-fill cols [kmax, S) for this strip's 64 rows (NT stores) ----
  const int col0 = nIt << 6;
  const int nvec = (S_LEN - col0) >> 2;
  if (nvec > 0) {
    const f32x4 z = {0.f, 0.f, 0.f, 0.f};
    for (int r = 0; r < 64; ++r) {
      float* rp = attn + bhSS + (size_t)(q0 + r) * S_LEN + col0;
      for (int i = tid; i < nvec; i += 256) nt_store4(rp + i * 4, z);
    }
  }
}

// ================== fallback (ws too small): R2 kernel verbatim ==================
__global__ __launch_bounds__(256) void sdpa_fb_kernel(
    const float* __restrict__ Qg, const float* __restrict__ Kg,
    const float* __restrict__ Vg, float* __restrict__ attn,
    float* __restrict__ outp) {
  const int bh = blockIdx.x >> 4;
  const int pi = blockIdx.x & 15;
  const int tid  = threadIdx.x;
  const int wave = tid >> 6;
  const int lane = tid & 63;
  const int g = lane >> 4;
  const int m = lane & 15;
  const int swzK = (m & 7) << 4;
  __shared__ __align__(16) unsigned short Kl[2][64 * 64];
  __shared__ __align__(16) unsigned short Vt[2][64 * 64];
  __shared__ __align__(16) unsigned short Pl[4][16 * 64];
  char* const PB = (char*)(&Pl[wave][0]);
  const size_t bhSD = (size_t)bh * (S_LEN * D_HEAD);
  const size_t bhSS = (size_t)bh * ((size_t)S_LEN * S_LEN);
  int ss[4], dd[4], koff[4];
  #pragma unroll
  for (int j = 0; j < 4; ++j) {
    int f = tid + j * 256;
    ss[j] = f >> 4;
    dd[j] = (f & 15) << 2;
    koff[j] = (((ss[j] << 6) + dd[j]) << 1) ^ ((ss[j] & 7) << 4);
  }
  int vro[4], vsz[4];
  #pragma unroll
  for (int dc = 0; dc < 4; ++dc) {
    int d = dc * 16 + m;
    vro[dc] = d << 7;
    vsz[dc] = ((d >> 2) & 7) << 4;
  }
  const float SCL = 0.18033688011112042f;
  for (int sidx = 0; sidx < 2; ++sidx) {
    const int qt = sidx ? (31 - pi) : pi;
    const int q0 = qt << 6;
    const int kmax = q0 + 64;
    const int nIter = kmax >> 6;
    const int qwrow = q0 + wave * 16;
    const int qbase = qwrow + g * 4;
    short8 aq0, aq1;
    {
      const float* qp = Qg + bhSD + (size_t)(qwrow + m) * D_HEAD + g * 8;
      float4 x0 = *(const float4*)(qp);
      float4 x1 = *(const float4*)(qp + 4);
      float4 y0 = *(const float4*)(qp + 32);
      float4 y1 = *(const float4*)(qp + 36);
      aq0[0]=(short)f2b(x0.x*SCL); aq0[1]=(short)f2b(x0.y*SCL);
      aq0[2]=(short)f2b(x0.z*SCL); aq0[3]=(short)f2b(x0.w*SCL);
      aq0[4]=(short)f2b(x1.x*SCL); aq0[5]=(short)f2b(x1.y*SCL);
      aq0[6]=(short)f2b(x1.z*SCL); aq0[7]=(short)f2b(x1.w*SCL);
      aq1[0]=(short)f2b(y0.x*SCL); aq1[1]=(short)f2b(y0.y*SCL);
      aq1[2]=(short)f2b(y0.z*SCL); aq1[3]=(short)f2b(y0.w*SCL);
      aq1[4]=(short)f2b(y1.x*SCL); aq1[5]=(short)f2b(y1.y*SCL);
      aq1[6]=(short)f2b(y1.z*SCL); aq1[7]=(short)f2b(y1.w*SCL);
    }
    float rs0 = 0.f, rs1 = 0.f, rs2 = 0.f, rs3 = 0.f;
    {
      float4 kr[4];
      #pragma unroll
      for (int j = 0; j < 4; ++j)
        kr[j] = *(const float4*)(Kg + bhSD + (size_t)ss[j] * D_HEAD + dd[j]);
      #pragma unroll
      for (int j = 0; j < 4; ++j) {
        ushort4 kb;
        kb.x = f2b(kr[j].x); kb.y = f2b(kr[j].y);
        kb.z = f2b(kr[j].z); kb.w = f2b(kr[j].w);
        *(ushort4*)((char*)Kl[0] + koff[j]) = kb;
      }
    }
    __syncthreads();
    int cur = 0;
    for (int it = 0; it < nIter; ++it) {
      const int kc = it << 6;
      const bool pf = (it + 1 < nIter);
      float4 kr[4];
      if (pf) {
        #pragma unroll
        for (int j = 0; j < 4; ++j)
          kr[j] = *(const float4*)(Kg + bhSD + (size_t)(kc + 64 + ss[j]) * D_HEAD + dd[j]);
      }
      const char* KB = (const char*)Kl[cur];
      #pragma unroll
      for (int t = 0; t < 4; ++t) {
        f32x4 acc = {0.f, 0.f, 0.f, 0.f};
        const int rb = (t * 16 + m) << 7;
        short8 b0 = *(const short8*)(KB + ((rb + g * 16) ^ swzK));
        short8 b1 = *(const short8*)(KB + ((rb + 64 + g * 16) ^ swzK));
        acc = __builtin_amdgcn_mfma_f32_16x16x32_bf16(aq0, b0, acc, 0, 0, 0);
        acc = __builtin_amdgcn_mfma_f32_16x16x32_bf16(aq1, b1, acc, 0, 0, 0);
        const int kcol = kc + t * 16 + m;
        rs0 += (kcol <= qbase + 0) ? exp2f(acc[0]) : 0.f;
        rs1 += (kcol <= qbase + 1) ? exp2f(acc[1]) : 0.f;
        rs2 += (kcol <= qbase + 2) ? exp2f(acc[2]) : 0.f;
        rs3 += (kcol <= qbase + 3) ? exp2f(acc[3]) : 0.f;
      }
      if (pf) {
        #pragma unroll
        for (int j = 0; j < 4; ++j) {
          ushort4 kb;
          kb.x = f2b(kr[j].x); kb.y = f2b(kr[j].y);
          kb.z = f2b(kr[j].z); kb.w = f2b(kr[j].w);
          *(ushort4*)((char*)Kl[cur ^ 1] + koff[j]) = kb;
        }
      }
      __syncthreads();
      cur ^= 1;
    }
    #pragma unroll
    for (int sft = 1; sft < 16; sft <<= 1) {
      rs0 += __shfl_xor(rs0, sft, 64);
      rs1 += __shfl_xor(rs1, sft, 64);
      rs2 += __shfl_xor(rs2, sft, 64);
      rs3 += __shfl_xor(rs3, sft, 64);
    }
    const float ri0 = 1.f / rs0, ri1 = 1.f / rs1, ri2 = 1.f / rs2, ri3 = 1.f / rs3;
    f32x4 o0 = {0.f,0.f,0.f,0.f}, o1 = {0.f,0.f,0.f,0.f};
    f32x4 o2 = {0.f,0.f,0.f,0.f}, o3 = {0.f,0.f,0.f,0.f};
    {
      float4 kr[4], vr[4];
      #pragma unroll
      for (int j = 0; j < 4; ++j) {
        kr[j] = *(const float4*)(Kg + bhSD + (size_t)ss[j] * D_HEAD + dd[j]);
        vr[j] = *(const float4*)(Vg + bhSD + (size_t)ss[j] * D_HEAD + dd[j]);
      }
      #pragma unroll
      for (int j = 0; j < 4; ++j) {
        ushort4 kb;
        kb.x = f2b(kr[j].x); kb.y = f2b(kr[j].y);
        kb.z = f2b(kr[j].z); kb.w = f2b(kr[j].w);
        *(ushort4*)((char*)Kl[0] + koff[j]) = kb;
        const int d0 = dd[j], s2 = ss[j] << 1;
        char* VB1 = (char*)Vt[0];
        *(unsigned short*)(VB1 + ((((d0+0)<<7) + s2) ^ ((((d0+0)>>2)&7)<<4))) = f2b(vr[j].x);
        *(unsigned short*)(VB1 + ((((d0+1)<<7) + s2) ^ ((((d0+1)>>2)&7)<<4))) = f2b(vr[j].y);
        *(unsigned short*)(VB1 + ((((d0+2)<<7) + s2) ^ ((((d0+2)>>2)&7)<<4))) = f2b(vr[j].z);
        *(unsigned short*)(VB1 + ((((d0+3)<<7) + s2) ^ ((((d0+3)>>2)&7)<<4))) = f2b(vr[j].w);
      }
    }
    __syncthreads();
    cur = 0;
    for (int it = 0; it < nIter; ++it) {
      const int kc = it << 6;
      const bool pf = (it + 1 < nIter);
      float4 kr[4], vr[4];
      if (pf) {
        #pragma unroll
        for (int j = 0; j < 4; ++j) {
          kr[j] = *(const float4*)(Kg + bhSD + (size_t)(kc + 64 + ss[j]) * D_HEAD + dd[j]);
          vr[j] = *(const float4*)(Vg + bhSD + (size_t)(kc + 64 + ss[j]) * D_HEAD + dd[j]);
        }
      }
      const char* KB = (const char*)Kl[cur];
      const char* VB = (const char*)Vt[cur];
      float* arow = attn + bhSS + (size_t)qbase * S_LEN + kc;
      #pragma unroll
      for (int t = 0; t < 4; ++t) {
        f32x4 acc = {0.f, 0.f, 0.f, 0.f};
        const int rb = (t * 16 + m) << 7;
        short8 b0 = *(const short8*)(KB + ((rb + g * 16) ^ swzK));
        short8 b1 = *(const short8*)(KB + ((rb + 64 + g * 16) ^ swzK));
        acc = __builtin_amdgcn_mfma_f32_16x16x32_bf16(aq0, b0, acc, 0, 0, 0);
        acc = __builtin_amdgcn_mfma_f32_16x16x32_bf16(aq1, b1, acc, 0, 0, 0);
        const int kcol = kc + t * 16 + m;
        const int tc = t * 16 + m;
        float p0 = (kcol <= qbase + 0) ? exp2f(acc[0]) * ri0 : 0.f;
        float p1 = (kcol <= qbase + 1) ? exp2f(acc[1]) * ri1 : 0.f;
        float p2 = (kcol <= qbase + 2) ? exp2f(acc[2]) * ri2 : 0.f;
        float p3 = (kcol <= qbase + 3) ? exp2f(acc[3]) * ri3 : 0.f;
        arow[0 * S_LEN + tc] = p0;
        arow[1 * S_LEN + tc] = p1;
        arow[2 * S_LEN + tc] = p2;
        arow[3 * S_LEN + tc] = p3;
        const int r0 = g * 4, c2 = tc << 1;
        *(unsigned short*)(PB + ((((r0+0)<<7) + c2) ^ (((r0+0)&7)<<4))) = f2b(p0);
        *(unsigned short*)(PB + ((((r0+1)<<7) + c2) ^ (((r0+1)&7)<<4))) = f2b(p1);
        *(unsigned short*)(PB + ((((r0+2)<<7) + c2) ^ (((r0+2)&7)<<4))) = f2b(p2);
        *(unsigned short*)(PB + ((((r0+3)<<7) + c2) ^ (((r0+3)&7)<<4))) = f2b(p3);
      }
      short8 pa0 = *(const short8*)(PB + (((m << 7) + g * 16) ^ swzK));
      short8 pa1 = *(const short8*)(PB + (((m << 7) + 64 + g * 16) ^ swzK));
      #pragma unroll
      for (int dc = 0; dc < 4; ++dc) {
        short8 bv0 = *(const short8*)(VB + ((vro[dc] + g * 16) ^ vsz[dc]));
        short8 bv1 = *(const short8*)(VB + ((vro[dc] + 64 + g * 16) ^ vsz[dc]));
        f32x4& od = (dc == 0) ? o0 : (dc == 1) ? o1 : (dc == 2) ? o2 : o3;
        od = __builtin_amdgcn_mfma_f32_16x16x32_bf16(pa0, bv0, od, 0, 0, 0);
        od = __builtin_amdgcn_mfma_f32_16x16x32_bf16(pa1, bv1, od, 0, 0, 0);
      }
      if (pf) {
        #pragma unroll
        for (int j = 0; j < 4; ++j) {
          ushort4 kb;
          kb.x = f2b(kr[j].x); kb.y = f2b(kr[j].y);
          kb.z = f2b(kr[j].z); kb.w = f2b(kr[j].w);
          *(ushort4*)((char*)Kl[cur ^ 1] + koff[j]) = kb;
          const int d0 = dd[j], s2 = ss[j] << 1;
          char* VB1 = (char*)Vt[cur ^ 1];
          *(unsigned short*)(VB1 + ((((d0+0)<<7) + s2) ^ ((((d0+0)>>2)&7)<<4))) = f2b(vr[j].x);
          *(unsigned short*)(VB1 + ((((d0+1)<<7) + s2) ^ ((((d0+1)>>2)&7)<<4))) = f2b(vr[j].y);
          *(unsigned short*)(VB1 + ((((d0+2)<<7) + s2) ^ ((((d0+2)>>2)&7)<<4))) = f2b(vr[j].z);
          *(unsigned short*)(VB1 + ((((d0+3)<<7) + s2) ^ ((((d0+3)>>2)&7)<<4))) = f2b(vr[j].w);
        }
      }
      __syncthreads();
      cur ^= 1;
    }
    #pragma unroll
    for (int reg = 0; reg < 4; ++reg) {
      float* op = outp + bhSD + (size_t)(qbase + reg) * D_HEAD + m;
      op[ 0] = o0[reg];
      op[16] = o1[reg];
      op[32] = o2[reg];
      op[48] = o3[reg];
    }
    const int ncols = S_LEN - kmax;
    if (ncols > 0) {
      const float4 z = {0.f, 0.f, 0.f, 0.f};
      const int nvec = ncols >> 2;
      for (int r = 0; r < 64; ++r) {
        float4* rp = (float4*)(attn + bhSS + (size_t)(q0 + r) * S_LEN + kmax);
        for (int i = tid; i < nvec; i += 256) rp[i] = z;
      }
    }
  }
}

extern "C" void kernel_launch(void* const* d_in, const int* in_sizes, int n_in,
                              void* d_out, int out_size, void* d_ws, size_t ws_size,
                              hipStream_t stream) {
  (void)in_sizes; (void)n_in; (void)out_size;
  const float* q = (const float*)d_in[0];
  const float* k = (const float*)d_in[1];
  const float* v = (const float*)d_in[2];
  float* attn = (float*)d_out;
  float* outp = attn + (size_t)2 * 16 * 2048 * 2048;
  const size_t pre_bytes = (size_t)32 * NTILES * TILE_B;   // 8.39 MB per tensor
  if (ws_size >= 2 * pre_bytes) {
    char* Kpre = (char*)d_ws;
    char* Vpre = Kpre + pre_bytes;
    convert_kv_kernel<<<2048, 256, 0, stream>>>(k, v, Kpre, Vpre);
    sdpa_pre_kernel<<<1024, 256, 0, stream>>>(q, Kpre, Vpre, attn, outp);
  } else {
    sdpa_fb_kernel<<<512, 256, 0, stream>>>(q, k, v, attn, outp);
  }
}